// Round 2
// baseline (1964.861 us; speedup 1.0000x reference)
//
#include <hip/hip_runtime.h>
#include <math.h>

// ---------------- constants from the reference ----------------
#define T_ 3
#define R_ 4
#define L_ 2
#define H_ 256
#define HEADS_ 8
#define D_ 32
#define FIN_ 128
#define OUT_ 128

typedef unsigned short bf16_t;

__device__ __forceinline__ float bf2f(bf16_t h) {
    return __uint_as_float(((unsigned)h) << 16);
}
__device__ __forceinline__ bf16_t f2bf(float f) {
    unsigned u = __float_as_uint(f);
    u += 0x7FFFu + ((u >> 16) & 1u);          // round-to-nearest-even
    return (bf16_t)(u >> 16);
}
__device__ __forceinline__ float gelu_exact(float x) {
    return 0.5f * x * (1.0f + erff(x * 0.70710678118654752440f));
}
// monotone float<->uint encoding for atomicMax on floats
__device__ __forceinline__ unsigned f2ord(float f) {
    unsigned u = __float_as_uint(f);
    return (u >> 31) ? ~u : (u | 0x80000000u);
}
__device__ __forceinline__ float ord2f(unsigned e) {
    return (e >> 31) ? __uint_as_float(e & 0x7fffffffu) : __uint_as_float(~e);
}

// ---------------- zero fill (capture-safe memset replacement) ----------------
__global__ void zero_kernel(unsigned* __restrict__ p, long n) {
    long i = (long)blockIdx.x * blockDim.x + threadIdx.x;
    long stride = (long)gridDim.x * blockDim.x;
    for (; i < n; i += stride) p[i] = 0u;
}

// ---------------- generic tiled GEMM ----------------
// C[M,Nc] = actC( actA(A)[M,K] @ B[K,Nc] + bias[Nc] )
// TA: float or bf16_t.  TC: float or bf16_t.  ACT_A: 1=exact gelu.  ACT_C: 1=relu.
#define BM 64
#define BN 64
#define BK 16

template<typename TA, typename TC, int ACT_A, int ACT_C>
__global__ __launch_bounds__(256) void gemm_kernel(
    const TA* __restrict__ A, const float* __restrict__ B,
    const float* __restrict__ bias, TC* __restrict__ C,
    int M, int K, int Nc)
{
    __shared__ float As[BK][BM + 4];
    __shared__ float Bs[BK][BN + 4];
    const int tid = threadIdx.x;
    const int bm = blockIdx.y * BM;
    const int bn = blockIdx.x * BN;
    const int tx = tid & 15;        // n-group
    const int ty = tid >> 4;        // m-group
    float acc[4][4] = {};

    for (int k0 = 0; k0 < K; k0 += BK) {
        // A tile: 64 rows x 16 k ; each thread loads 4 consecutive k
        {
            int idx = tid * 4;              // 0..1023
            int row = idx / BK;             // 0..63
            int kk  = idx % BK;             // 0,4,8,12
            int arow = bm + row;
            float4 a4 = make_float4(0.f, 0.f, 0.f, 0.f);
            if (arow < M) {
                if constexpr (sizeof(TA) == 4) {
                    a4 = *reinterpret_cast<const float4*>(A + (size_t)arow * K + k0 + kk);
                } else {
                    ushort4 u = *reinterpret_cast<const ushort4*>(A + (size_t)arow * K + k0 + kk);
                    a4.x = bf2f(u.x); a4.y = bf2f(u.y); a4.z = bf2f(u.z); a4.w = bf2f(u.w);
                }
            }
            if (ACT_A == 1) {
                a4.x = gelu_exact(a4.x); a4.y = gelu_exact(a4.y);
                a4.z = gelu_exact(a4.z); a4.w = gelu_exact(a4.w);
            }
            As[kk + 0][row] = a4.x; As[kk + 1][row] = a4.y;
            As[kk + 2][row] = a4.z; As[kk + 3][row] = a4.w;
        }
        // B tile: 16 k x 64 n (B always fp32 weights)
        {
            int idx = tid * 4;
            int kk = idx / BN;
            int nn = idx % BN;
            float4 b4 = *reinterpret_cast<const float4*>(B + (size_t)(k0 + kk) * Nc + bn + nn);
            *reinterpret_cast<float4*>(&Bs[kk][nn]) = b4;
        }
        __syncthreads();
        #pragma unroll
        for (int kk = 0; kk < BK; ++kk) {
            float a[4], b[4];
            #pragma unroll
            for (int i = 0; i < 4; ++i) a[i] = As[kk][ty * 4 + i];
            #pragma unroll
            for (int j = 0; j < 4; ++j) b[j] = Bs[kk][tx * 4 + j];
            #pragma unroll
            for (int i = 0; i < 4; ++i)
                #pragma unroll
                for (int j = 0; j < 4; ++j)
                    acc[i][j] += a[i] * b[j];
        }
        __syncthreads();
    }

    #pragma unroll
    for (int i = 0; i < 4; ++i) {
        int row = bm + ty * 4 + i;
        if (row >= M) continue;
        int col0 = bn + tx * 4;
        float vv[4];
        #pragma unroll
        for (int j = 0; j < 4; ++j) {
            vv[j] = acc[i][j] + bias[col0 + j];
            if (ACT_C == 1) vv[j] = fmaxf(vv[j], 0.f);
        }
        if constexpr (sizeof(TC) == 4) {
            float4 o4 = make_float4(vv[0], vv[1], vv[2], vv[3]);
            *reinterpret_cast<float4*>(C + (size_t)row * Nc + col0) = o4;
        } else {
            ushort4 o4;
            o4.x = f2bf(vv[0]); o4.y = f2bf(vv[1]); o4.z = f2bf(vv[2]); o4.w = f2bf(vv[3]);
            *reinterpret_cast<ushort4*>(C + (size_t)row * Nc + col0) = o4;
        }
    }
}

// ---------------- weight/bias fusion: Wf = W @ blockdiag(a_rel) ----------------
// W: [H,H] fp32, A: [HEADS][D][D] fp32, Wf: [H,H] fp32
__global__ __launch_bounds__(256) void fuse_w_kernel(
    const float* __restrict__ W, const float* __restrict__ A,
    float* __restrict__ Wf)
{
    __shared__ float As[HEADS_ * D_ * D_];   // 32 KB
    __shared__ float Wrow[H_];
    const int tid = threadIdx.x;
    const int k = blockIdx.x;
    for (int i = tid; i < HEADS_ * D_ * D_; i += 256) As[i] = A[i];
    Wrow[tid] = W[(size_t)k * H_ + tid];
    __syncthreads();
    const int hh = tid >> 5, e = tid & 31;
    float acc = 0.f;
    #pragma unroll
    for (int d = 0; d < D_; ++d)
        acc += Wrow[hh * D_ + d] * As[(hh * D_ + d) * D_ + e];
    Wf[(size_t)k * H_ + tid] = acc;
}

__global__ void fuse_b_kernel(const float* __restrict__ b,
                              const float* __restrict__ A,
                              float* __restrict__ bf)
{
    const int tid = threadIdx.x;   // 256
    const int hh = tid >> 5, e = tid & 31;
    float acc = 0.f;
    #pragma unroll
    for (int d = 0; d < D_; ++d)
        acc += b[hh * D_ + d] * A[(hh * D_ + d) * D_ + e];
    bf[tid] = acc;
}

// ---------------- edge kernels ----------------
__global__ __launch_bounds__(256) void edge_logits_kernel(
    const int* __restrict__ src, const int* __restrict__ dst,
    const bf16_t* __restrict__ q, const bf16_t* __restrict__ kr,
    const float* __restrict__ p_rel, float scale,
    float* __restrict__ logits, unsigned* __restrict__ mOrd, int E)
{
    int idx = blockIdx.x * 256 + threadIdx.x;
    if (idx >= E * HEADS_) return;
    int e = idx >> 3, h = idx & 7;
    int s = src[e], d = dst[e];
    const ushort4* qp = reinterpret_cast<const ushort4*>(q + (size_t)d * H_ + h * D_);
    const ushort4* kp = reinterpret_cast<const ushort4*>(kr + (size_t)s * H_ + h * D_);
    float acc = 0.f;
    #pragma unroll
    for (int i = 0; i < 8; ++i) {
        ushort4 a = qp[i], b = kp[i];
        acc += bf2f(a.x) * bf2f(b.x) + bf2f(a.y) * bf2f(b.y)
             + bf2f(a.z) * bf2f(b.z) + bf2f(a.w) * bf2f(b.w);
    }
    float lg = acc * p_rel[h] * scale;
    logits[idx] = lg;
    atomicMax(mOrd + (size_t)d * HEADS_ + h, f2ord(lg));
}

__global__ __launch_bounds__(256) void edge_expsum_kernel(
    const int* __restrict__ dst, float* __restrict__ logits,
    const unsigned* __restrict__ mOrd, float* __restrict__ ssum, int E)
{
    int idx = blockIdx.x * 256 + threadIdx.x;
    if (idx >= E * HEADS_) return;
    int e = idx >> 3, h = idx & 7;
    int d = dst[e];
    float m = ord2f(mOrd[(size_t)d * HEADS_ + h]);
    float a = expf(logits[idx] - m);
    logits[idx] = a;                      // alpha in place
    atomicAdd(ssum + (size_t)d * HEADS_ + h, a);
}

__global__ __launch_bounds__(256) void edge_agg_kernel(
    const int* __restrict__ src, const int* __restrict__ dst,
    const bf16_t* __restrict__ vr, const float* __restrict__ alpha,
    const float* __restrict__ ssum, float* __restrict__ agg, int E)
{
    int e = blockIdx.x;
    int c = threadIdx.x;          // 0..255
    int h = c >> 5;
    int s = src[e], d = dst[e];
    float a = alpha[(size_t)e * HEADS_ + h] / ssum[(size_t)d * HEADS_ + h];
    float vv = bf2f(vr[(size_t)s * H_ + c]);
    atomicAdd(agg + (size_t)d * H_ + c, vv * a);
}

// ---------------- fused skip-gate + residual + LN + ReLU ----------------
// h_row <- relu( LN( beta*o + (2-beta)*h ) * g + b )
__global__ __launch_bounds__(256) void skip_ln_kernel(
    bf16_t* __restrict__ h, const bf16_t* __restrict__ o,
    const float* __restrict__ skip, const float* __restrict__ ln_g,
    const float* __restrict__ ln_b, int Nn)
{
    const int wave = threadIdx.x >> 6;
    const int lane = threadIdx.x & 63;
    long row = (long)blockIdx.x * 4 + wave;
    long total = (long)T_ * Nn;
    if (row >= total) return;
    int t = (int)(row / Nn);
    float beta = 1.f / (1.f + expf(-skip[t]));
    float cb = 2.f - beta;
    ushort4 hv = reinterpret_cast<const ushort4*>(h + row * H_)[lane];
    ushort4 ov = reinterpret_cast<const ushort4*>(o + row * H_)[lane];
    float u0 = beta * bf2f(ov.x) + cb * bf2f(hv.x);
    float u1 = beta * bf2f(ov.y) + cb * bf2f(hv.y);
    float u2 = beta * bf2f(ov.z) + cb * bf2f(hv.z);
    float u3 = beta * bf2f(ov.w) + cb * bf2f(hv.w);
    float s1 = u0 + u1 + u2 + u3;
    float s2 = u0 * u0 + u1 * u1 + u2 * u2 + u3 * u3;
    #pragma unroll
    for (int off = 1; off < 64; off <<= 1) {
        s1 += __shfl_xor(s1, off);
        s2 += __shfl_xor(s2, off);
    }
    float mu = s1 * (1.f / H_);
    float var = s2 * (1.f / H_) - mu * mu;
    float inv = rsqrtf(var + 1e-5f);
    const float4 g = reinterpret_cast<const float4*>(ln_g + (size_t)t * H_)[lane];
    const float4 b = reinterpret_cast<const float4*>(ln_b + (size_t)t * H_)[lane];
    ushort4 r;
    r.x = f2bf(fmaxf((u0 - mu) * inv * g.x + b.x, 0.f));
    r.y = f2bf(fmaxf((u1 - mu) * inv * g.y + b.y, 0.f));
    r.z = f2bf(fmaxf((u2 - mu) * inv * g.z + b.z, 0.f));
    r.w = f2bf(fmaxf((u3 - mu) * inv * g.w + b.w, 0.f));
    reinterpret_cast<ushort4*>(h + row * H_)[lane] = r;
}

// ---------------- host side ----------------
extern "C" void kernel_launch(void* const* d_in, const int* in_sizes, int n_in,
                              void* d_out, int out_size, void* d_ws, size_t ws_size,
                              hipStream_t stream)
{
    const float* x     = (const float*)d_in[0];
    const int*   ei    = (const int*)  d_in[1];
    const float* Win   = (const float*)d_in[2];
    const float* b_in  = (const float*)d_in[3];
    const float* Wk    = (const float*)d_in[4];
    const float* bk    = (const float*)d_in[5];
    const float* Wq    = (const float*)d_in[6];
    const float* bq    = (const float*)d_in[7];
    const float* Wv    = (const float*)d_in[8];
    const float* bv    = (const float*)d_in[9];
    const float* Wa    = (const float*)d_in[10];
    const float* ba    = (const float*)d_in[11];
    const float* skip  = (const float*)d_in[12];
    const float* a_rel = (const float*)d_in[13];
    const float* m_rel = (const float*)d_in[14];
    const float* p_rel = (const float*)d_in[15];
    const float* ln_g  = (const float*)d_in[16];
    const float* ln_b  = (const float*)d_in[17];
    const float* Wout  = (const float*)d_in[18];
    const float* bout  = (const float*)d_in[19];
    float* out = (float*)d_out;

    const int N = in_sizes[0] / (T_ * FIN_);
    const int E = in_sizes[1] / (R_ * 2);
    const size_t NH = (size_t)N * H_;

    static const int SRC_T[R_] = {0, 1, 1, 1};
    // relations grouped by destination type: dt=0:{r1}, dt=1:{r0,r2}, dt=2:{r3}
    const int GROUPS[3][2] = {{1, -1}, {0, 2}, {3, -1}};

    char* wp = (char*)d_ws;
    auto alloc = [&](size_t bytes) {
        void* r = wp;
        wp += (bytes + 255) & ~(size_t)255;
        return r;
    };
    bf16_t*   h      = (bf16_t*)alloc(T_ * NH * 2);          // 30.7 MB
    bf16_t*   q      = (bf16_t*)alloc(T_ * NH * 2);          // 30.7 MB (reused as o)
    float*    agg    = (float*) alloc(NH * 4);               // 20.5 MB (per dst-type)
    bf16_t*   kr     = (bf16_t*)alloc(NH * 2);               // 10.2 MB
    bf16_t*   vr     = (bf16_t*)alloc(NH * 2);               // 10.2 MB
    float*    logits = (float*) alloc((size_t)E * HEADS_ * 4);
    unsigned* mOrd   = (unsigned*)alloc((size_t)N * HEADS_ * 4);
    float*    ssum   = (float*) alloc((size_t)N * HEADS_ * 4);
    float*    Wkf    = (float*) alloc((size_t)H_ * H_ * 4);
    float*    Wvf    = (float*) alloc((size_t)H_ * H_ * 4);
    float*    bkf    = (float*) alloc(H_ * 4);
    float*    bvf    = (float*) alloc(H_ * 4);

    // diagnostic guard: if workspace is too small, do nothing (clean absmax fail
    // instead of a memory-fault crash distinguishes the failure mode)
    if ((size_t)(wp - (char*)d_ws) > ws_size) return;

    const float scale = 0.17677669529663688f;  // 1/sqrt(32)
    dim3 blk(256);
    auto ggrid = [](int M, int Nc) { return dim3(Nc / BN, (M + BM - 1) / BM); };

    // input projection + relu: x fp32 -> h bf16
    for (int t = 0; t < T_; ++t)
        gemm_kernel<float, bf16_t, 0, 1><<<ggrid(N, H_), blk, 0, stream>>>(
            x + (size_t)t * N * FIN_, Win + (size_t)t * FIN_ * H_, b_in + t * H_,
            h + t * NH, N, FIN_, H_);

    for (int l = 0; l < L_; ++l) {
        // q for all 3 node types
        for (int t = 0; t < T_; ++t) {
            size_t wOff = ((size_t)l * T_ + t) * H_ * H_;
            size_t bOff = ((size_t)l * T_ + t) * H_;
            gemm_kernel<bf16_t, bf16_t, 0, 0><<<ggrid(N, H_), blk, 0, stream>>>(
                h + t * NH, Wq + wOff, bq + bOff, q + t * NH, N, H_, H_);
        }
        for (int g = 0; g < 3; ++g) {
            const int dt = g;
            zero_kernel<<<2048, blk, 0, stream>>>((unsigned*)agg, (long)NH);
            for (int gi = 0; gi < 2; ++gi) {
                int r = GROUPS[g][gi];
                if (r < 0) continue;
                int st = SRC_T[r];
                const int* srcp = ei + (size_t)r * 2 * E;
                const int* dstp = srcp + E;
                size_t relOff = ((size_t)l * R_ + r) * HEADS_ * D_ * D_;
                size_t wOff = ((size_t)l * T_ + st) * H_ * H_;
                size_t bOff = ((size_t)l * T_ + st) * H_;
                fuse_w_kernel<<<H_, blk, 0, stream>>>(Wk + wOff, a_rel + relOff, Wkf);
                fuse_b_kernel<<<1, blk, 0, stream>>>(bk + bOff, a_rel + relOff, bkf);
                fuse_w_kernel<<<H_, blk, 0, stream>>>(Wv + wOff, m_rel + relOff, Wvf);
                fuse_b_kernel<<<1, blk, 0, stream>>>(bv + bOff, m_rel + relOff, bvf);
                gemm_kernel<bf16_t, bf16_t, 0, 0><<<ggrid(N, H_), blk, 0, stream>>>(
                    h + st * NH, Wkf, bkf, kr, N, H_, H_);
                gemm_kernel<bf16_t, bf16_t, 0, 0><<<ggrid(N, H_), blk, 0, stream>>>(
                    h + st * NH, Wvf, bvf, vr, N, H_, H_);
                zero_kernel<<<640, blk, 0, stream>>>(mOrd, (long)N * HEADS_);
                zero_kernel<<<640, blk, 0, stream>>>((unsigned*)ssum, (long)N * HEADS_);
                int tot = E * HEADS_;
                edge_logits_kernel<<<(tot + 255) / 256, blk, 0, stream>>>(
                    srcp, dstp, q + (size_t)dt * NH, kr,
                    p_rel + ((size_t)l * R_ + r) * HEADS_, scale, logits, mOrd, E);
                edge_expsum_kernel<<<(tot + 255) / 256, blk, 0, stream>>>(
                    dstp, logits, mOrd, ssum, E);
                edge_agg_kernel<<<E, blk, 0, stream>>>(
                    srcp, dstp, vr, logits, ssum, agg, E);
            }
            // o[dt] = gelu(agg) @ Wa + ba   (o aliases q[dt]; q[dt] is dead now)
            size_t wOff = ((size_t)l * T_ + dt) * H_ * H_;
            size_t bOff = ((size_t)l * T_ + dt) * H_;
            gemm_kernel<float, bf16_t, 1, 0><<<ggrid(N, H_), blk, 0, stream>>>(
                agg, Wa + wOff, ba + bOff, q + (size_t)dt * NH, N, H_, H_);
        }
        skip_ln_kernel<<<((size_t)T_ * N + 3) / 4, blk, 0, stream>>>(
            h, q, skip + l * T_, ln_g + (size_t)l * T_ * H_, ln_b + (size_t)l * T_ * H_, N);
    }

    // shared output projection over all types at once: h bf16 -> out fp32
    gemm_kernel<bf16_t, float, 0, 0><<<ggrid(T_ * N, OUT_), blk, 0, stream>>>(
        h, Wout, bout, out, T_ * N, H_, OUT_);
}

// Round 3
// 1117.951 us; speedup vs baseline: 1.7576x; 1.7576x over previous
//
#include <hip/hip_runtime.h>
#include <math.h>

// ---------------- constants from the reference ----------------
#define T_ 3
#define R_ 4
#define L_ 2
#define H_ 256
#define HEADS_ 8
#define D_ 32
#define FIN_ 128
#define OUT_ 128

typedef unsigned short bf16_t;
typedef __attribute__((ext_vector_type(8))) short bf16x8;
typedef __attribute__((ext_vector_type(4))) float f32x4;

__device__ __forceinline__ float bf2f(bf16_t h) {
    return __uint_as_float(((unsigned)h) << 16);
}
__device__ __forceinline__ bf16_t f2bf(float f) {
    unsigned u = __float_as_uint(f);
    u += 0x7FFFu + ((u >> 16) & 1u);          // round-to-nearest-even
    return (bf16_t)(u >> 16);
}
__device__ __forceinline__ float gelu_exact(float x) {
    return 0.5f * x * (1.0f + erff(x * 0.70710678118654752440f));
}
// monotone float<->uint encoding for atomicMax on floats
__device__ __forceinline__ unsigned f2ord(float f) {
    unsigned u = __float_as_uint(f);
    return (u >> 31) ? ~u : (u | 0x80000000u);
}
__device__ __forceinline__ float ord2f(unsigned e) {
    return (e >> 31) ? __uint_as_float(e & 0x7fffffffu) : __uint_as_float(~e);
}

// ---------------- zero fill (capture-safe memset replacement) ----------------
__global__ void zero_kernel(unsigned* __restrict__ p, long n) {
    long i = (long)blockIdx.x * blockDim.x + threadIdx.x;
    long stride = (long)gridDim.x * blockDim.x;
    for (; i < n; i += stride) p[i] = 0u;
}

// ---------------- fp32 -> bf16 convert (optional exact-GELU) ----------------
template<int GELU>
__global__ void conv_kernel(const float* __restrict__ in, bf16_t* __restrict__ out, long n) {
    long i = (long)blockIdx.x * blockDim.x + threadIdx.x;
    long stride = (long)gridDim.x * blockDim.x;
    for (; i < n; i += stride) {
        float v = in[i];
        if (GELU) v = gelu_exact(v);
        out[i] = f2bf(v);
    }
}

// ---------------- batched transpose+convert: [S][Rr][Cc] f32 -> [S][Cc][Rr] bf16 ----------------
__global__ __launch_bounds__(256) void transconv_kernel(
    const float* __restrict__ in, bf16_t* __restrict__ out, int Rr, int Cc)
{
    __shared__ float Ls[64][65];
    const int tid = threadIdx.x;
    const long base = (long)blockIdx.z * Rr * Cc;
    const int r0 = blockIdx.y * 64, c0 = blockIdx.x * 64;
    #pragma unroll
    for (int i = 0; i < 16; ++i) {
        int e = tid + i * 256; int row = e >> 6, col = e & 63;
        Ls[row][col] = in[base + (long)(r0 + row) * Cc + c0 + col];
    }
    __syncthreads();
    #pragma unroll
    for (int i = 0; i < 16; ++i) {
        int e = tid + i * 256; int row = e >> 6, col = e & 63;
        out[base + (long)(c0 + row) * Rr + r0 + col] = f2bf(Ls[col][row]);
    }
}

// ---------------- fused relation weights, transposed bf16 output ----------------
// slice s = (l*4+r)*2 + kv ;  WfT[s][col][k] = sum_d W[k][hh*32+d] * A[hh][d][e], col=hh*32+e
__global__ __launch_bounds__(256) void fuse_wT_kernel(
    const float* __restrict__ Wk, const float* __restrict__ Wv,
    const float* __restrict__ a_rel, const float* __restrict__ m_rel,
    bf16_t* __restrict__ WfT)
{
    const int s = blockIdx.z;
    const int kv = s & 1, r = (s >> 1) & 3, l = s >> 3;
    const int SRCT[4] = {0, 1, 1, 1};
    const int st = SRCT[r];
    const float* W = (kv ? Wv : Wk) + ((long)l * T_ + st) * H_ * H_;
    const float* A = (kv ? m_rel : a_rel) + ((long)l * R_ + r) * HEADS_ * D_ * D_;
    const int hh = blockIdx.y, kt = blockIdx.x;
    __shared__ float As[32][33];
    __shared__ float Ws[64][33];
    const int tid = threadIdx.x;
    {   // A[hh]: 32x32
        int d = tid >> 3, e4 = (tid & 7) * 4;
        float4 v = *(const float4*)(A + (hh * D_ + d) * D_ + e4);
        As[d][e4] = v.x; As[d][e4 + 1] = v.y; As[d][e4 + 2] = v.z; As[d][e4 + 3] = v.w;
    }
    #pragma unroll
    for (int p = 0; p < 2; ++p) {   // W[kt*64..+63][hh*32..+31]
        int idx = p * 256 + tid;
        int row = idx >> 3, c4 = (idx & 7) * 4;
        float4 v = *(const float4*)(W + (long)(kt * 64 + row) * H_ + hh * 32 + c4);
        Ws[row][c4] = v.x; Ws[row][c4 + 1] = v.y; Ws[row][c4 + 2] = v.z; Ws[row][c4 + 3] = v.w;
    }
    __syncthreads();
    const int kl = tid & 63, eb = tid >> 6;
    #pragma unroll
    for (int ii = 0; ii < 8; ++ii) {
        int e = eb * 8 + ii;
        float acc = 0.f;
        #pragma unroll
        for (int d = 0; d < 32; ++d)
            acc += As[d][e] * Ws[kl][d];
        WfT[((long)s * H_ + hh * 32 + e) * H_ + kt * 64 + kl] = f2bf(acc);
    }
}

__global__ void fuse_b_kernel(
    const float* __restrict__ bk, const float* __restrict__ bv,
    const float* __restrict__ a_rel, const float* __restrict__ m_rel,
    float* __restrict__ bf_out)
{
    const int s = blockIdx.x;
    const int kv = s & 1, r = (s >> 1) & 3, l = s >> 3;
    const int SRCT[4] = {0, 1, 1, 1};
    const int st = SRCT[r];
    const float* b = (kv ? bv : bk) + ((long)l * T_ + st) * H_;
    const float* A = (kv ? m_rel : a_rel) + ((long)l * R_ + r) * HEADS_ * D_ * D_;
    const int tid = threadIdx.x;
    const int hh = tid >> 5, e = tid & 31;
    float acc = 0.f;
    #pragma unroll
    for (int d = 0; d < D_; ++d)
        acc += b[hh * D_ + d] * A[(hh * D_ + d) * D_ + e];
    bf_out[s * H_ + tid] = acc;
}

// ---------------- MFMA bf16 GEMM ----------------
// C[M,Nc] = actC( A[M,K] @ BT[Nc,K]^T + bias[Nc] ), batched over blockIdx.z.
// A bf16 row-major, BT bf16 [Nc][K] (i.e., B transposed), bias fp32.
// Tile 128x128, 4 waves (2x2), BK=32, mfma_f32_16x16x32_bf16.
template<typename TC, int ACT_C>
__global__ __launch_bounds__(256) void mfma_gemm(
    const bf16_t* __restrict__ A, const bf16_t* __restrict__ BT,
    const float* __restrict__ bias, TC* __restrict__ C,
    int M, int K, int Nc,
    long strideA, long strideB, long strideBias, long strideC)
{
    const bf16_t* Ab = A + (long)blockIdx.z * strideA;
    const bf16_t* Bb = BT + (long)blockIdx.z * strideB;
    const float* biasb = bias + (long)blockIdx.z * strideBias;
    TC* Cb = C + (long)blockIdx.z * strideC;

    __shared__ bf16_t As[128 * 32];
    __shared__ bf16_t Bs[128 * 32];
    const int tid = threadIdx.x;
    const int lane = tid & 63, wave = tid >> 6;
    const int wr = wave >> 1, wc = wave & 1;
    const int bm = blockIdx.y * 128, bn = blockIdx.x * 128;
    const int r16 = lane & 15, g = lane >> 4;
    f32x4 acc[4][4] = {};

    for (int k0 = 0; k0 < K; k0 += 32) {
        #pragma unroll
        for (int p = 0; p < 2; ++p) {
            int idx = p * 256 + tid;          // 0..511
            int row = idx >> 2, seg = idx & 3;
            int grow = bm + row;
            bf16x8 av = {};
            if (grow < M) av = *(const bf16x8*)(Ab + (long)grow * K + k0 + seg * 8);
            *(bf16x8*)(As + row * 32 + seg * 8) = av;
            bf16x8 bv = *(const bf16x8*)(Bb + (long)(bn + row) * K + k0 + seg * 8);
            *(bf16x8*)(Bs + row * 32 + seg * 8) = bv;
        }
        __syncthreads();
        bf16x8 af[4], bfr[4];
        #pragma unroll
        for (int m = 0; m < 4; ++m)
            af[m] = *(const bf16x8*)(As + (wr * 64 + m * 16 + r16) * 32 + g * 8);
        #pragma unroll
        for (int n = 0; n < 4; ++n)
            bfr[n] = *(const bf16x8*)(Bs + (wc * 64 + n * 16 + r16) * 32 + g * 8);
        #pragma unroll
        for (int m = 0; m < 4; ++m)
            #pragma unroll
            for (int n = 0; n < 4; ++n)
                acc[m][n] = __builtin_amdgcn_mfma_f32_16x16x32_bf16(af[m], bfr[n], acc[m][n], 0, 0, 0);
        __syncthreads();
    }

    #pragma unroll
    for (int n = 0; n < 4; ++n) {
        int col = bn + wc * 64 + n * 16 + r16;
        float bb = biasb[col];
        #pragma unroll
        for (int m = 0; m < 4; ++m) {
            int rowbase = bm + wr * 64 + m * 16 + g * 4;
            #pragma unroll
            for (int j = 0; j < 4; ++j) {
                int row = rowbase + j;
                if (row < M) {
                    float vv = acc[m][n][j] + bb;
                    if (ACT_C) vv = fmaxf(vv, 0.f);
                    if constexpr (sizeof(TC) == 4)
                        Cb[(long)row * Nc + col] = vv;
                    else
                        Cb[(long)row * Nc + col] = f2bf(vv);
                }
            }
        }
    }
}

// ---------------- edge kernels ----------------
__global__ __launch_bounds__(256) void edge_logits_kernel(
    const int* __restrict__ src, const int* __restrict__ dst,
    const bf16_t* __restrict__ q, const bf16_t* __restrict__ kr,
    const float* __restrict__ p_rel, float scale,
    float* __restrict__ logits, unsigned* __restrict__ mOrd, int E)
{
    int idx = blockIdx.x * 256 + threadIdx.x;
    if (idx >= E * HEADS_) return;
    int e = idx >> 3, h = idx & 7;
    int s = src[e], d = dst[e];
    const ushort4* qp = reinterpret_cast<const ushort4*>(q + (size_t)d * H_ + h * D_);
    const ushort4* kp = reinterpret_cast<const ushort4*>(kr + (size_t)s * H_ + h * D_);
    float acc = 0.f;
    #pragma unroll
    for (int i = 0; i < 8; ++i) {
        ushort4 a = qp[i], b = kp[i];
        acc += bf2f(a.x) * bf2f(b.x) + bf2f(a.y) * bf2f(b.y)
             + bf2f(a.z) * bf2f(b.z) + bf2f(a.w) * bf2f(b.w);
    }
    float lg = acc * p_rel[h] * scale;
    logits[idx] = lg;
    atomicMax(mOrd + (size_t)d * HEADS_ + h, f2ord(lg));
}

__global__ __launch_bounds__(256) void edge_expsum_kernel(
    const int* __restrict__ dst, float* __restrict__ logits,
    const unsigned* __restrict__ mOrd, float* __restrict__ ssum, int E)
{
    int idx = blockIdx.x * 256 + threadIdx.x;
    if (idx >= E * HEADS_) return;
    int e = idx >> 3, h = idx & 7;
    int d = dst[e];
    float m = ord2f(mOrd[(size_t)d * HEADS_ + h]);
    float a = expf(logits[idx] - m);
    logits[idx] = a;                      // alpha in place
    atomicAdd(ssum + (size_t)d * HEADS_ + h, a);
}

__global__ __launch_bounds__(256) void edge_agg_kernel(
    const int* __restrict__ src, const int* __restrict__ dst,
    const bf16_t* __restrict__ vr, const float* __restrict__ alpha,
    const float* __restrict__ ssum, float* __restrict__ agg, int E)
{
    int e = blockIdx.x;
    int c = threadIdx.x;          // 0..255
    int h = c >> 5;
    int s = src[e], d = dst[e];
    float a = alpha[(size_t)e * HEADS_ + h] / ssum[(size_t)d * HEADS_ + h];
    float vv = bf2f(vr[(size_t)s * H_ + c]);
    atomicAdd(agg + (size_t)d * H_ + c, vv * a);
}

// ---------------- fused skip-gate + residual + LN + ReLU ----------------
__global__ __launch_bounds__(256) void skip_ln_kernel(
    bf16_t* __restrict__ h, const bf16_t* __restrict__ o,
    const float* __restrict__ skip, const float* __restrict__ ln_g,
    const float* __restrict__ ln_b, int Nn)
{
    const int wave = threadIdx.x >> 6;
    const int lane = threadIdx.x & 63;
    long row = (long)blockIdx.x * 4 + wave;
    long total = (long)T_ * Nn;
    if (row >= total) return;
    int t = (int)(row / Nn);
    float beta = 1.f / (1.f + expf(-skip[t]));
    float cb = 2.f - beta;
    ushort4 hv = reinterpret_cast<const ushort4*>(h + row * H_)[lane];
    ushort4 ov = reinterpret_cast<const ushort4*>(o + row * H_)[lane];
    float u0 = beta * bf2f(ov.x) + cb * bf2f(hv.x);
    float u1 = beta * bf2f(ov.y) + cb * bf2f(hv.y);
    float u2 = beta * bf2f(ov.z) + cb * bf2f(hv.z);
    float u3 = beta * bf2f(ov.w) + cb * bf2f(hv.w);
    float s1 = u0 + u1 + u2 + u3;
    float s2 = u0 * u0 + u1 * u1 + u2 * u2 + u3 * u3;
    #pragma unroll
    for (int off = 1; off < 64; off <<= 1) {
        s1 += __shfl_xor(s1, off);
        s2 += __shfl_xor(s2, off);
    }
    float mu = s1 * (1.f / H_);
    float var = s2 * (1.f / H_) - mu * mu;
    float inv = rsqrtf(var + 1e-5f);
    const float4 g = reinterpret_cast<const float4*>(ln_g + (size_t)t * H_)[lane];
    const float4 b = reinterpret_cast<const float4*>(ln_b + (size_t)t * H_)[lane];
    ushort4 r;
    r.x = f2bf(fmaxf((u0 - mu) * inv * g.x + b.x, 0.f));
    r.y = f2bf(fmaxf((u1 - mu) * inv * g.y + b.y, 0.f));
    r.z = f2bf(fmaxf((u2 - mu) * inv * g.z + b.z, 0.f));
    r.w = f2bf(fmaxf((u3 - mu) * inv * g.w + b.w, 0.f));
    reinterpret_cast<ushort4*>(h + row * H_)[lane] = r;
}

// ---------------- host side ----------------
extern "C" void kernel_launch(void* const* d_in, const int* in_sizes, int n_in,
                              void* d_out, int out_size, void* d_ws, size_t ws_size,
                              hipStream_t stream)
{
    const float* x     = (const float*)d_in[0];
    const int*   ei    = (const int*)  d_in[1];
    const float* Win   = (const float*)d_in[2];
    const float* b_in  = (const float*)d_in[3];
    const float* Wk    = (const float*)d_in[4];
    const float* bk    = (const float*)d_in[5];
    const float* Wq    = (const float*)d_in[6];
    const float* bq    = (const float*)d_in[7];
    const float* Wv    = (const float*)d_in[8];
    const float* bv    = (const float*)d_in[9];
    const float* Wa    = (const float*)d_in[10];
    const float* ba    = (const float*)d_in[11];
    const float* skip  = (const float*)d_in[12];
    const float* a_rel = (const float*)d_in[13];
    const float* m_rel = (const float*)d_in[14];
    const float* p_rel = (const float*)d_in[15];
    const float* ln_g  = (const float*)d_in[16];
    const float* ln_b  = (const float*)d_in[17];
    const float* Wout  = (const float*)d_in[18];
    const float* bout  = (const float*)d_in[19];
    float* out = (float*)d_out;

    const int N = in_sizes[0] / (T_ * FIN_);
    const int E = in_sizes[1] / (R_ * 2);
    const size_t NH = (size_t)N * H_;

    static const int SRC_T[R_] = {0, 1, 1, 1};
    // relations grouped by destination type: dt=0:{r1}, dt=1:{r0,r2}, dt=2:{r3}
    const int GROUPS[3][2] = {{1, -1}, {0, 2}, {3, -1}};

    char* wp = (char*)d_ws;
    auto alloc = [&](size_t bytes) {
        void* r = wp;
        wp += (bytes + 255) & ~(size_t)255;
        return r;
    };
    bf16_t*   h      = (bf16_t*)alloc(T_ * NH * 2);          // 30.7 MB
    bf16_t*   q      = (bf16_t*)alloc(T_ * NH * 2);          // 30.7 MB (reused as o)
    float*    agg    = (float*) alloc(NH * 4);               // 20.5 MB
    bf16_t*   krvr   = (bf16_t*)alloc(2 * NH * 2);           // 20.5 MB: kr | vr ; aliases xb & aggb
    float*    logits = (float*) alloc((size_t)E * HEADS_ * 4);
    unsigned* mOrd   = (unsigned*)alloc((size_t)N * HEADS_ * 4);
    float*    ssum   = (float*) alloc((size_t)N * HEADS_ * 4);   // contiguous with mOrd
    bf16_t*   WqT    = (bf16_t*)alloc((size_t)L_ * T_ * H_ * H_ * 2);
    bf16_t*   WaT    = (bf16_t*)alloc((size_t)L_ * T_ * H_ * H_ * 2);
    bf16_t*   WinT   = (bf16_t*)alloc((size_t)T_ * FIN_ * H_ * 2);
    bf16_t*   WoutT  = (bf16_t*)alloc((size_t)H_ * OUT_ * 2);
    bf16_t*   WkvfT  = (bf16_t*)alloc((size_t)16 * H_ * H_ * 2);
    float*    bkvf   = (float*) alloc((size_t)16 * H_ * 4);

    bf16_t* kr   = krvr;
    bf16_t* vr   = krvr + NH;
    bf16_t* xb   = krvr;                 // [T][N][FIN] bf16, used before kr/vr
    bf16_t* aggb = krvr;                 // [N][H] bf16, used after kr/vr dead

    if ((size_t)(wp - (char*)d_ws) > ws_size) return;   // clean-fail guard

    const float scale = 0.17677669529663688f;  // 1/sqrt(32)
    dim3 blk(256);
    auto gM = [](long M) { return (int)((M + 127) / 128); };

    // ---- weight preprocessing (once per call) ----
    transconv_kernel<<<dim3(4, 4, L_ * T_), blk, 0, stream>>>(Wq, WqT, H_, H_);
    transconv_kernel<<<dim3(4, 4, L_ * T_), blk, 0, stream>>>(Wa, WaT, H_, H_);
    transconv_kernel<<<dim3(4, 2, T_),      blk, 0, stream>>>(Win, WinT, FIN_, H_);
    transconv_kernel<<<dim3(2, 4, 1),       blk, 0, stream>>>(Wout, WoutT, H_, OUT_);
    fuse_wT_kernel<<<dim3(4, 8, 16), blk, 0, stream>>>(Wk, Wv, a_rel, m_rel, WkvfT);
    fuse_b_kernel<<<16, blk, 0, stream>>>(bk, bv, a_rel, m_rel, bkvf);

    // ---- input projection + relu (batched over t) ----
    conv_kernel<0><<<2048, blk, 0, stream>>>(x, xb, (long)T_ * N * FIN_);
    mfma_gemm<bf16_t, 1><<<dim3(H_ / 128, gM(N), T_), blk, 0, stream>>>(
        xb, WinT, b_in, h, N, FIN_, H_,
        (long)N * FIN_, (long)FIN_ * H_, H_, (long)NH);

    for (int l = 0; l < L_; ++l) {
        // q for all 3 node types (batched)
        mfma_gemm<bf16_t, 0><<<dim3(H_ / 128, gM(N), T_), blk, 0, stream>>>(
            h, WqT + (size_t)l * T_ * H_ * H_, bq + (size_t)l * T_ * H_, q,
            N, H_, H_, (long)NH, (long)H_ * H_, H_, (long)NH);

        for (int g = 0; g < 3; ++g) {
            const int dt = g;
            zero_kernel<<<2048, blk, 0, stream>>>((unsigned*)agg, (long)NH);
            for (int gi = 0; gi < 2; ++gi) {
                int r = GROUPS[g][gi];
                if (r < 0) continue;
                int st = SRC_T[r];
                const int* srcp = ei + (size_t)r * 2 * E;
                const int* dstp = srcp + E;
                int sl = (l * R_ + r) * 2;
                // kr and vr in one batched GEMM (z = 2)
                mfma_gemm<bf16_t, 0><<<dim3(H_ / 128, gM(N), 2), blk, 0, stream>>>(
                    h + st * NH, WkvfT + (size_t)sl * H_ * H_, bkvf + (size_t)sl * H_, kr,
                    N, H_, H_, 0L, (long)H_ * H_, H_, (long)NH);
                zero_kernel<<<640, blk, 0, stream>>>(mOrd, 2L * N * HEADS_);  // mOrd + ssum
                int tot = E * HEADS_;
                edge_logits_kernel<<<(tot + 255) / 256, blk, 0, stream>>>(
                    srcp, dstp, q + (size_t)dt * NH, kr,
                    p_rel + ((size_t)l * R_ + r) * HEADS_, scale, logits, mOrd, E);
                edge_expsum_kernel<<<(tot + 255) / 256, blk, 0, stream>>>(
                    dstp, logits, mOrd, ssum, E);
                edge_agg_kernel<<<E, blk, 0, stream>>>(
                    srcp, dstp, vr, logits, ssum, agg, E);
            }
            // gelu(agg) -> bf16, then o[dt] = aggb @ Wa + ba   (o aliases q[dt])
            conv_kernel<1><<<2048, blk, 0, stream>>>(agg, aggb, (long)NH);
            mfma_gemm<bf16_t, 0><<<dim3(H_ / 128, gM(N), 1), blk, 0, stream>>>(
                aggb, WaT + ((size_t)l * T_ + dt) * H_ * H_, ba + ((size_t)l * T_ + dt) * H_,
                q + (size_t)dt * NH, N, H_, H_, 0L, 0L, 0L, 0L);
        }
        skip_ln_kernel<<<((size_t)T_ * N + 3) / 4, blk, 0, stream>>>(
            h, q, skip + l * T_, ln_g + (size_t)l * T_ * H_, ln_b + (size_t)l * T_ * H_, N);
    }

    // shared output projection over all types at once: h bf16 -> out fp32
    mfma_gemm<float, 0><<<dim3(OUT_ / 128, gM((long)T_ * N), 1), blk, 0, stream>>>(
        h, WoutT, bout, out, T_ * N, H_, OUT_, 0L, 0L, 0L, 0L);
}

// Round 5
// 724.043 us; speedup vs baseline: 2.7137x; 1.5440x over previous
//
#include <hip/hip_runtime.h>
#include <math.h>

// ---------------- constants from the reference ----------------
#define T_ 3
#define R_ 4
#define L_ 2
#define H_ 256
#define HEADS_ 8
#define D_ 32
#define FIN_ 128
#define OUT_ 128

typedef unsigned short bf16_t;
typedef __attribute__((ext_vector_type(8))) short bf16x8;
typedef __attribute__((ext_vector_type(4))) float f32x4;

__device__ __forceinline__ float bf2f(bf16_t h) {
    return __uint_as_float(((unsigned)h) << 16);
}
__device__ __forceinline__ bf16_t f2bf(float f) {
    unsigned u = __float_as_uint(f);
    u += 0x7FFFu + ((u >> 16) & 1u);          // round-to-nearest-even
    return (bf16_t)(u >> 16);
}
__device__ __forceinline__ float gelu_exact(float x) {
    return 0.5f * x * (1.0f + erff(x * 0.70710678118654752440f));
}

// ---------------- zero fill (capture-safe memset replacement) ----------------
__global__ void zero_kernel(unsigned* __restrict__ p, long n) {
    long i = (long)blockIdx.x * blockDim.x + threadIdx.x;
    long stride = (long)gridDim.x * blockDim.x;
    for (; i < n; i += stride) p[i] = 0u;
}

// ---------------- fp32 -> bf16 convert ----------------
__global__ void conv_kernel(const float* __restrict__ in, bf16_t* __restrict__ out, long n) {
    long i = (long)blockIdx.x * blockDim.x + threadIdx.x;
    long stride = (long)gridDim.x * blockDim.x;
    for (; i < n; i += stride) out[i] = f2bf(in[i]);
}

// ---------------- batched transpose+convert: [S][Rr][Cc] f32 -> [S][Cc][Rr] bf16 ----------------
__global__ __launch_bounds__(256) void transconv_kernel(
    const float* __restrict__ in, bf16_t* __restrict__ out, int Rr, int Cc)
{
    __shared__ float Ls[64][65];
    const int tid = threadIdx.x;
    const long base = (long)blockIdx.z * Rr * Cc;
    const int r0 = blockIdx.y * 64, c0 = blockIdx.x * 64;
    #pragma unroll
    for (int i = 0; i < 16; ++i) {
        int e = tid + i * 256; int row = e >> 6, col = e & 63;
        Ls[row][col] = in[base + (long)(r0 + row) * Cc + c0 + col];
    }
    __syncthreads();
    #pragma unroll
    for (int i = 0; i < 16; ++i) {
        int e = tid + i * 256; int row = e >> 6, col = e & 63;
        out[base + (long)(c0 + row) * Rr + r0 + col] = f2bf(Ls[col][row]);
    }
}

// ---------------- fused relation weights, transposed bf16 output ----------------
// slice s = (l*4+r)*2 + kv ;  WfT[s][col][k] = sum_d W[k][hh*32+d] * A[hh][d][e], col=hh*32+e
__global__ __launch_bounds__(256) void fuse_wT_kernel(
    const float* __restrict__ Wk, const float* __restrict__ Wv,
    const float* __restrict__ a_rel, const float* __restrict__ m_rel,
    bf16_t* __restrict__ WfT)
{
    const int s = blockIdx.z;
    const int kv = s & 1, r = (s >> 1) & 3, l = s >> 3;
    const int SRCT[4] = {0, 1, 1, 1};
    const int st = SRCT[r];
    const float* W = (kv ? Wv : Wk) + ((long)l * T_ + st) * H_ * H_;
    const float* A = (kv ? m_rel : a_rel) + ((long)l * R_ + r) * HEADS_ * D_ * D_;
    const int hh = blockIdx.y, kt = blockIdx.x;
    __shared__ float As[32][33];
    __shared__ float Ws[64][33];
    const int tid = threadIdx.x;
    {   // A[hh]: 32x32
        int d = tid >> 3, e4 = (tid & 7) * 4;
        float4 v = *(const float4*)(A + (hh * D_ + d) * D_ + e4);
        As[d][e4] = v.x; As[d][e4 + 1] = v.y; As[d][e4 + 2] = v.z; As[d][e4 + 3] = v.w;
    }
    #pragma unroll
    for (int p = 0; p < 2; ++p) {   // W[kt*64..+63][hh*32..+31]
        int idx = p * 256 + tid;
        int row = idx >> 3, c4 = (idx & 7) * 4;
        float4 v = *(const float4*)(W + (long)(kt * 64 + row) * H_ + hh * 32 + c4);
        Ws[row][c4] = v.x; Ws[row][c4 + 1] = v.y; Ws[row][c4 + 2] = v.z; Ws[row][c4 + 3] = v.w;
    }
    __syncthreads();
    const int kl = tid & 63, eb = tid >> 6;
    #pragma unroll
    for (int ii = 0; ii < 8; ++ii) {
        int e = eb * 8 + ii;
        float acc = 0.f;
        #pragma unroll
        for (int d = 0; d < 32; ++d)
            acc += As[d][e] * Ws[kl][d];
        WfT[((long)s * H_ + hh * 32 + e) * H_ + kt * 64 + kl] = f2bf(acc);
    }
}

__global__ void fuse_b_kernel(
    const float* __restrict__ bk, const float* __restrict__ bv,
    const float* __restrict__ a_rel, const float* __restrict__ m_rel,
    float* __restrict__ bf_out)
{
    const int s = blockIdx.x;
    const int kv = s & 1, r = (s >> 1) & 3, l = s >> 3;
    const int SRCT[4] = {0, 1, 1, 1};
    const int st = SRCT[r];
    const float* b = (kv ? bv : bk) + ((long)l * T_ + st) * H_;
    const float* A = (kv ? m_rel : a_rel) + ((long)l * R_ + r) * HEADS_ * D_ * D_;
    const int tid = threadIdx.x;
    const int hh = tid >> 5, e = tid & 31;
    float acc = 0.f;
    #pragma unroll
    for (int d = 0; d < D_; ++d)
        acc += b[hh * D_ + d] * A[(hh * D_ + d) * D_ + e];
    bf_out[s * H_ + tid] = acc;
}

// ---------------- CSR build (per relation, by destination) ----------------
__global__ void hist_kernel(const int* __restrict__ ei, int* __restrict__ indeg,
                            int Nn, int E)
{
    int idx = blockIdx.x * 256 + threadIdx.x;
    if (idx >= R_ * E) return;
    int r = idx / E, e = idx - r * E;
    int d = ei[(size_t)r * 2 * E + E + e];
    atomicAdd(indeg + (size_t)r * Nn + d, 1);
}

__global__ __launch_bounds__(256) void scan_kernel(
    const int* __restrict__ indeg, int* __restrict__ offs,
    int* __restrict__ cursor, int Nn)
{
    __shared__ int part[256];
    const int r = blockIdx.x;
    const int tid = threadIdx.x;
    const int chunk = (Nn + 255) / 256;
    int beg = tid * chunk, end = min(beg + chunk, Nn);
    int sum = 0;
    for (int i = beg; i < end; ++i) sum += indeg[(size_t)r * Nn + i];
    part[tid] = sum;
    __syncthreads();
    for (int off = 1; off < 256; off <<= 1) {
        int v = (tid >= off) ? part[tid - off] : 0;
        __syncthreads();
        part[tid] += v;
        __syncthreads();
    }
    int run = (tid == 0) ? 0 : part[tid - 1];
    for (int i = beg; i < end; ++i) {
        offs[(size_t)r * (Nn + 1) + i] = run;
        cursor[(size_t)r * Nn + i] = run;
        run += indeg[(size_t)r * Nn + i];
    }
    if (tid == 255) offs[(size_t)r * (Nn + 1) + Nn] = run;
}

__global__ void scatter_kernel(const int* __restrict__ ei, int* __restrict__ cursor,
                               int* __restrict__ esrc, int Nn, int E)
{
    int idx = blockIdx.x * 256 + threadIdx.x;
    if (idx >= R_ * E) return;
    int r = idx / E, e = idx - r * E;
    int s = ei[(size_t)r * 2 * E + e];
    int d = ei[(size_t)r * 2 * E + E + e];
    int pos = atomicAdd(cursor + (size_t)r * Nn + d, 1);
    esrc[(size_t)r * E + pos] = s;
}

// ---------------- fused per-node attention aggregation ----------------
// One wave per destination node. IMPORTANT: the reference computes an
// INDEPENDENT segment-softmax per relation and SUMS the per-relation weighted
// aggregates — so (m, s, acc) reset per relation; normalized results are added.
// aggb MAY alias qdt (wave reads own q row before writing own agg row).
template<int NREL>
__global__ __launch_bounds__(256) void agg_fused_kernel(
    const int* __restrict__ offs0, const int* __restrict__ esrc0,
    const int* __restrict__ offs1, const int* __restrict__ esrc1,
    const bf16_t* __restrict__ qdt,
    const bf16_t* __restrict__ kr0, const bf16_t* __restrict__ vr0,
    const bf16_t* __restrict__ kr1, const bf16_t* __restrict__ vr1,
    const float* __restrict__ p0, const float* __restrict__ p1,
    float scale, bf16_t* __restrict__ aggb, int Nn)
{
    const int wave = threadIdx.x >> 6;
    const int lane = threadIdx.x & 63;
    const int d = blockIdx.x * 4 + wave;
    if (d >= Nn) return;
    const int head = lane >> 3;    // 8 lanes per head, 4 channels per lane

    ushort4 qu = ((const ushort4*)(qdt + (size_t)d * H_))[lane];
    float q0 = bf2f(qu.x), q1 = bf2f(qu.y), q2 = bf2f(qu.z), q3 = bf2f(qu.w);

    float t0 = 0.f, t1 = 0.f, t2 = 0.f, t3 = 0.f;   // sum over relations

    #pragma unroll
    for (int rr = 0; rr < NREL; ++rr) {
        const int* offs = rr ? offs1 : offs0;
        const int* esrc = rr ? esrc1 : esrc0;
        const bf16_t* kr = rr ? kr1 : kr0;
        const bf16_t* vr = rr ? vr1 : vr0;
        const float pr = (rr ? p1 : p0)[head] * scale;
        float m = -INFINITY, s = 0.f;
        float a0 = 0.f, a1 = 0.f, a2 = 0.f, a3 = 0.f;
        int beg = offs[d], end = offs[d + 1];
        for (int e = beg; e < end; ++e) {
            int si = esrc[e];
            ushort4 ku = ((const ushort4*)(kr + (size_t)si * H_))[lane];
            ushort4 vu = ((const ushort4*)(vr + (size_t)si * H_))[lane];
            float dt = q0 * bf2f(ku.x) + q1 * bf2f(ku.y) + q2 * bf2f(ku.z) + q3 * bf2f(ku.w);
            dt += __shfl_xor(dt, 1);
            dt += __shfl_xor(dt, 2);
            dt += __shfl_xor(dt, 4);
            float lg = dt * pr;
            float mnew = fmaxf(m, lg);
            float fac = __expf(m - mnew);        // 0 when m==-inf
            float p = __expf(lg - mnew);
            s = s * fac + p;
            a0 = a0 * fac + p * bf2f(vu.x);
            a1 = a1 * fac + p * bf2f(vu.y);
            a2 = a2 * fac + p * bf2f(vu.z);
            a3 = a3 * fac + p * bf2f(vu.w);
            m = mnew;
        }
        float invs = (s > 0.f) ? 1.f / s : 0.f;
        t0 += a0 * invs;
        t1 += a1 * invs;
        t2 += a2 * invs;
        t3 += a3 * invs;
    }
    ushort4 ou;
    ou.x = f2bf(gelu_exact(t0));
    ou.y = f2bf(gelu_exact(t1));
    ou.z = f2bf(gelu_exact(t2));
    ou.w = f2bf(gelu_exact(t3));
    ((ushort4*)(aggb + (size_t)d * H_))[lane] = ou;
}

// ---------------- MFMA bf16 GEMM ----------------
// C[M,Nc] = actC( A[M,K] @ BT[Nc,K]^T + bias[Nc] ), batched over blockIdx.z.
template<typename TC, int ACT_C>
__global__ __launch_bounds__(256) void mfma_gemm(
    const bf16_t* __restrict__ A, const bf16_t* __restrict__ BT,
    const float* __restrict__ bias, TC* __restrict__ C,
    int M, int K, int Nc,
    long strideA, long strideB, long strideBias, long strideC)
{
    const bf16_t* Ab = A + (long)blockIdx.z * strideA;
    const bf16_t* Bb = BT + (long)blockIdx.z * strideB;
    const float* biasb = bias + (long)blockIdx.z * strideBias;
    TC* Cb = C + (long)blockIdx.z * strideC;

    __shared__ bf16_t As[128 * 32];
    __shared__ bf16_t Bs[128 * 32];
    const int tid = threadIdx.x;
    const int lane = tid & 63, wave = tid >> 6;
    const int wr = wave >> 1, wc = wave & 1;
    const int bm = blockIdx.y * 128, bn = blockIdx.x * 128;
    const int r16 = lane & 15, g = lane >> 4;
    f32x4 acc[4][4] = {};

    for (int k0 = 0; k0 < K; k0 += 32) {
        #pragma unroll
        for (int p = 0; p < 2; ++p) {
            int idx = p * 256 + tid;
            int row = idx >> 2, seg = idx & 3;
            int grow = bm + row;
            bf16x8 av = {};
            if (grow < M) av = *(const bf16x8*)(Ab + (long)grow * K + k0 + seg * 8);
            *(bf16x8*)(As + row * 32 + seg * 8) = av;
            bf16x8 bv = *(const bf16x8*)(Bb + (long)(bn + row) * K + k0 + seg * 8);
            *(bf16x8*)(Bs + row * 32 + seg * 8) = bv;
        }
        __syncthreads();
        bf16x8 af[4], bfr[4];
        #pragma unroll
        for (int m = 0; m < 4; ++m)
            af[m] = *(const bf16x8*)(As + (wr * 64 + m * 16 + r16) * 32 + g * 8);
        #pragma unroll
        for (int n = 0; n < 4; ++n)
            bfr[n] = *(const bf16x8*)(Bs + (wc * 64 + n * 16 + r16) * 32 + g * 8);
        #pragma unroll
        for (int m = 0; m < 4; ++m)
            #pragma unroll
            for (int n = 0; n < 4; ++n)
                acc[m][n] = __builtin_amdgcn_mfma_f32_16x16x32_bf16(af[m], bfr[n], acc[m][n], 0, 0, 0);
        __syncthreads();
    }

    #pragma unroll
    for (int n = 0; n < 4; ++n) {
        int col = bn + wc * 64 + n * 16 + r16;
        float bb = biasb[col];
        #pragma unroll
        for (int m = 0; m < 4; ++m) {
            int rowbase = bm + wr * 64 + m * 16 + g * 4;
            #pragma unroll
            for (int j = 0; j < 4; ++j) {
                int row = rowbase + j;
                if (row < M) {
                    float vv = acc[m][n][j] + bb;
                    if (ACT_C) vv = fmaxf(vv, 0.f);
                    if constexpr (sizeof(TC) == 4)
                        Cb[(long)row * Nc + col] = vv;
                    else
                        Cb[(long)row * Nc + col] = f2bf(vv);
                }
            }
        }
    }
}

// ---------------- fused skip-gate + residual + LN + ReLU ----------------
__global__ __launch_bounds__(256) void skip_ln_kernel(
    bf16_t* __restrict__ h,
    const bf16_t* __restrict__ o0, const bf16_t* __restrict__ o1,
    const bf16_t* __restrict__ o2,
    const float* __restrict__ skip, const float* __restrict__ ln_g,
    const float* __restrict__ ln_b, int Nn)
{
    const int wave = threadIdx.x >> 6;
    const int lane = threadIdx.x & 63;
    long row = (long)blockIdx.x * 4 + wave;
    long total = (long)T_ * Nn;
    if (row >= total) return;
    int t = (int)(row / Nn);
    const bf16_t* op = (t == 0 ? o0 : t == 1 ? o1 : o2) + (row - (long)t * Nn) * H_;
    float beta = 1.f / (1.f + expf(-skip[t]));
    float cb = 2.f - beta;
    ushort4 hv = reinterpret_cast<const ushort4*>(h + row * H_)[lane];
    ushort4 ov = reinterpret_cast<const ushort4*>(op)[lane];
    float u0 = beta * bf2f(ov.x) + cb * bf2f(hv.x);
    float u1 = beta * bf2f(ov.y) + cb * bf2f(hv.y);
    float u2 = beta * bf2f(ov.z) + cb * bf2f(hv.z);
    float u3 = beta * bf2f(ov.w) + cb * bf2f(hv.w);
    float s1 = u0 + u1 + u2 + u3;
    float s2 = u0 * u0 + u1 * u1 + u2 * u2 + u3 * u3;
    #pragma unroll
    for (int off = 1; off < 64; off <<= 1) {
        s1 += __shfl_xor(s1, off);
        s2 += __shfl_xor(s2, off);
    }
    float mu = s1 * (1.f / H_);
    float var = s2 * (1.f / H_) - mu * mu;
    float inv = rsqrtf(var + 1e-5f);
    const float4 g = reinterpret_cast<const float4*>(ln_g + (size_t)t * H_)[lane];
    const float4 b = reinterpret_cast<const float4*>(ln_b + (size_t)t * H_)[lane];
    ushort4 r;
    r.x = f2bf(fmaxf((u0 - mu) * inv * g.x + b.x, 0.f));
    r.y = f2bf(fmaxf((u1 - mu) * inv * g.y + b.y, 0.f));
    r.z = f2bf(fmaxf((u2 - mu) * inv * g.z + b.z, 0.f));
    r.w = f2bf(fmaxf((u3 - mu) * inv * g.w + b.w, 0.f));
    reinterpret_cast<ushort4*>(h + row * H_)[lane] = r;
}

// ---------------- host side ----------------
extern "C" void kernel_launch(void* const* d_in, const int* in_sizes, int n_in,
                              void* d_out, int out_size, void* d_ws, size_t ws_size,
                              hipStream_t stream)
{
    const float* x     = (const float*)d_in[0];
    const int*   ei    = (const int*)  d_in[1];
    const float* Win   = (const float*)d_in[2];
    const float* b_in  = (const float*)d_in[3];
    const float* Wk    = (const float*)d_in[4];
    const float* bk    = (const float*)d_in[5];
    const float* Wq    = (const float*)d_in[6];
    const float* bq    = (const float*)d_in[7];
    const float* Wv    = (const float*)d_in[8];
    const float* bv    = (const float*)d_in[9];
    const float* Wa    = (const float*)d_in[10];
    const float* ba    = (const float*)d_in[11];
    const float* skip  = (const float*)d_in[12];
    const float* a_rel = (const float*)d_in[13];
    const float* m_rel = (const float*)d_in[14];
    const float* p_rel = (const float*)d_in[15];
    const float* ln_g  = (const float*)d_in[16];
    const float* ln_b  = (const float*)d_in[17];
    const float* Wout  = (const float*)d_in[18];
    const float* bout  = (const float*)d_in[19];
    float* out = (float*)d_out;

    const int N = in_sizes[0] / (T_ * FIN_);
    const int E = in_sizes[1] / (R_ * 2);
    const size_t NH = (size_t)N * H_;

    char* wp = (char*)d_ws;
    auto alloc = [&](size_t bytes) {
        void* r = wp;
        wp += (bytes + 255) & ~(size_t)255;
        return r;
    };
    bf16_t* h     = (bf16_t*)alloc(T_ * NH * 2);          // 30.7 MB
    bf16_t* qcur  = (bf16_t*)alloc(NH * 2);               // 10.2 MB (q AND agg per group)
    bf16_t* S     = (bf16_t*)alloc(4 * NH * 2);           // 41.0 MB: 4 kr/vr/o slots; xb alias
    int*    indeg = (int*)   alloc((size_t)R_ * N * 4);
    int*    offs  = (int*)   alloc((size_t)R_ * (N + 1) * 4);
    int*    cursor= (int*)   alloc((size_t)R_ * N * 4);
    int*    esrc  = (int*)   alloc((size_t)R_ * E * 4);
    bf16_t* WqT   = (bf16_t*)alloc((size_t)L_ * T_ * H_ * H_ * 2);
    bf16_t* WaT   = (bf16_t*)alloc((size_t)L_ * T_ * H_ * H_ * 2);
    bf16_t* WinT  = (bf16_t*)alloc((size_t)T_ * FIN_ * H_ * 2);
    bf16_t* WoutT = (bf16_t*)alloc((size_t)H_ * OUT_ * 2);
    bf16_t* WkvfT = (bf16_t*)alloc((size_t)16 * H_ * H_ * 2);
    float*  bkvf  = (float*) alloc((size_t)16 * H_ * 4);

    bf16_t* S0 = S;
    bf16_t* S1 = S + NH;
    bf16_t* S2 = S + 2 * NH;
    bf16_t* S3 = S + 3 * NH;
    bf16_t* xb = S;                       // [T][N][FIN] bf16, pre-layer only

    if ((size_t)(wp - (char*)d_ws) > ws_size) return;   // clean-fail guard

    const float scale = 0.17677669529663688f;  // 1/sqrt(32)
    dim3 blk(256);
    auto gM = [](long M) { return (int)((M + 127) / 128); };

    // ---- weight preprocessing ----
    transconv_kernel<<<dim3(4, 4, L_ * T_), blk, 0, stream>>>(Wq, WqT, H_, H_);
    transconv_kernel<<<dim3(4, 4, L_ * T_), blk, 0, stream>>>(Wa, WaT, H_, H_);
    transconv_kernel<<<dim3(4, 2, T_),      blk, 0, stream>>>(Win, WinT, FIN_, H_);
    transconv_kernel<<<dim3(2, 4, 1),       blk, 0, stream>>>(Wout, WoutT, H_, OUT_);
    fuse_wT_kernel<<<dim3(4, 8, 16), blk, 0, stream>>>(Wk, Wv, a_rel, m_rel, WkvfT);
    fuse_b_kernel<<<16, blk, 0, stream>>>(bk, bv, a_rel, m_rel, bkvf);

    // ---- CSR build (per relation, once per call) ----
    zero_kernel<<<256, blk, 0, stream>>>((unsigned*)indeg, (long)R_ * N);
    hist_kernel<<<(R_ * E + 255) / 256, blk, 0, stream>>>(ei, indeg, N, E);
    scan_kernel<<<R_, blk, 0, stream>>>(indeg, offs, cursor, N);
    scatter_kernel<<<(R_ * E + 255) / 256, blk, 0, stream>>>(ei, cursor, esrc, N, E);

    // ---- input projection + relu ----
    conv_kernel<<<2048, blk, 0, stream>>>(x, xb, (long)T_ * N * FIN_);
    mfma_gemm<bf16_t, 1><<<dim3(H_ / 128, gM(N), T_), blk, 0, stream>>>(
        xb, WinT, b_in, h, N, FIN_, H_,
        (long)N * FIN_, (long)FIN_ * H_, H_, (long)NH);

    // group schedule (order dt=1, dt=0, dt=2 for slot reuse):
    //   dt=1: rels r0(st0)->S0,S1  r2(st1)->S2,S3 ; o1 -> S0
    //   dt=0: rel  r1(st1)->S1,S2               ; o0 -> S3
    //   dt=2: rel  r3(st1)->S1,S2               ; o2 -> S2
    for (int l = 0; l < L_; ++l) {
        const int lT = l * T_;
        struct G { int dt; int r[2]; int st[2]; int nrel; bf16_t* slot[2]; bf16_t* odst; };
        G gs[3] = {
            {1, {0, 2}, {0, 1}, 2, {S0, S2}, S0},
            {0, {1,-1}, {1, 0}, 1, {S1, 0},  S3},
            {2, {3,-1}, {1, 0}, 1, {S1, 0},  S2},
        };
        for (int gi = 0; gi < 3; ++gi) {
            G& g = gs[gi];
            const int dt = g.dt;
            // kr/vr GEMMs (z=2 per relation: kr then vr)
            for (int j = 0; j < g.nrel; ++j) {
                int r = g.r[j], st = g.st[j];
                int sl = (l * R_ + r) * 2;
                mfma_gemm<bf16_t, 0><<<dim3(H_ / 128, gM(N), 2), blk, 0, stream>>>(
                    h + st * NH, WkvfT + (size_t)sl * H_ * H_, bkvf + (size_t)sl * H_,
                    g.slot[j], N, H_, H_, 0L, (long)H_ * H_, H_, (long)NH);
            }
            // q for this dst type
            mfma_gemm<bf16_t, 0><<<dim3(H_ / 128, gM(N), 1), blk, 0, stream>>>(
                h + dt * NH, WqT + (size_t)(lT + dt) * H_ * H_, bq + (size_t)(lT + dt) * H_,
                qcur, N, H_, H_, 0L, 0L, 0L, 0L);
            // fused per-node per-relation softmax aggregation + GELU (aggb aliases qcur)
            int r0i = g.r[0];
            const float* p0 = p_rel + ((size_t)l * R_ + r0i) * HEADS_;
            if (g.nrel == 2) {
                int r1i = g.r[1];
                const float* p1 = p_rel + ((size_t)l * R_ + r1i) * HEADS_;
                agg_fused_kernel<2><<<(N + 3) / 4, blk, 0, stream>>>(
                    offs + (size_t)r0i * (N + 1), esrc + (size_t)r0i * E,
                    offs + (size_t)r1i * (N + 1), esrc + (size_t)r1i * E,
                    qcur, g.slot[0], g.slot[0] + NH, g.slot[1], g.slot[1] + NH,
                    p0, p1, scale, qcur, N);
            } else {
                agg_fused_kernel<1><<<(N + 3) / 4, blk, 0, stream>>>(
                    offs + (size_t)r0i * (N + 1), esrc + (size_t)r0i * E,
                    (const int*)nullptr, (const int*)nullptr,
                    qcur, g.slot[0], g.slot[0] + NH, (const bf16_t*)nullptr, (const bf16_t*)nullptr,
                    p0, (const float*)nullptr, scale, qcur, N);
            }
            // o[dt] = aggb @ Wa + ba
            mfma_gemm<bf16_t, 0><<<dim3(H_ / 128, gM(N), 1), blk, 0, stream>>>(
                qcur, WaT + (size_t)(lT + dt) * H_ * H_, ba + (size_t)(lT + dt) * H_,
                g.odst, N, H_, H_, 0L, 0L, 0L, 0L);
        }
        skip_ln_kernel<<<((size_t)T_ * N + 3) / 4, blk, 0, stream>>>(
            h, /*o0=*/S3, /*o1=*/S0, /*o2=*/S2,
            skip + l * T_, ln_g + (size_t)l * T_ * H_, ln_b + (size_t)l * T_ * H_, N);
    }

    // shared output projection: h bf16 -> out fp32
    mfma_gemm<float, 0><<<dim3(OUT_ / 128, gM((long)T_ * N), 1), blk, 0, stream>>>(
        h, WoutT, bout, out, T_ * N, H_, OUT_, 0L, 0L, 0L, 0L);
}

// Round 6
// 565.706 us; speedup vs baseline: 3.4733x; 1.2799x over previous
//
#include <hip/hip_runtime.h>
#include <math.h>

// ---------------- constants from the reference ----------------
#define T_ 3
#define R_ 4
#define L_ 2
#define H_ 256
#define HEADS_ 8
#define D_ 32
#define FIN_ 128
#define OUT_ 128

typedef unsigned short bf16_t;
typedef __attribute__((ext_vector_type(8))) short bf16x8;
typedef __attribute__((ext_vector_type(4))) float f32x4;

__device__ __forceinline__ float bf2f(bf16_t h) {
    return __uint_as_float(((unsigned)h) << 16);
}
__device__ __forceinline__ bf16_t f2bf(float f) {
    unsigned u = __float_as_uint(f);
    u += 0x7FFFu + ((u >> 16) & 1u);          // round-to-nearest-even
    return (bf16_t)(u >> 16);
}
__device__ __forceinline__ float gelu_exact(float x) {
    return 0.5f * x * (1.0f + erff(x * 0.70710678118654752440f));
}

// ---------------- zero fill ----------------
__global__ void zero_kernel(unsigned* __restrict__ p, long n) {
    long i = (long)blockIdx.x * blockDim.x + threadIdx.x;
    long stride = (long)gridDim.x * blockDim.x;
    for (; i < n; i += stride) p[i] = 0u;
}

// ---------------- batched transpose+convert: [S][Rr][Cc] f32 -> [S][Cc][Rr] bf16 ----------------
__global__ __launch_bounds__(256) void transconv_kernel(
    const float* __restrict__ in, bf16_t* __restrict__ out, int Rr, int Cc)
{
    __shared__ float Ls[64][65];
    const int tid = threadIdx.x;
    const long base = (long)blockIdx.z * Rr * Cc;
    const int r0 = blockIdx.y * 64, c0 = blockIdx.x * 64;
    #pragma unroll
    for (int i = 0; i < 16; ++i) {
        int e = tid + i * 256; int row = e >> 6, col = e & 63;
        Ls[row][col] = in[base + (long)(r0 + row) * Cc + c0 + col];
    }
    __syncthreads();
    #pragma unroll
    for (int i = 0; i < 16; ++i) {
        int e = tid + i * 256; int row = e >> 6, col = e & 63;
        out[base + (long)(c0 + row) * Rr + r0 + col] = f2bf(Ls[col][row]);
    }
}

// ---------------- fused relation weights -> [l][r][kv*256+col][k] bf16 ----------------
// slice s=(l*4+r)*2+kv ; BT row index = (l*4+r)*512 + kv*256 + (hh*32+e)
__global__ __launch_bounds__(256) void fuse_wT_kernel(
    const float* __restrict__ Wk, const float* __restrict__ Wv,
    const float* __restrict__ a_rel, const float* __restrict__ m_rel,
    bf16_t* __restrict__ WkvT)
{
    const int s = blockIdx.z;
    const int kv = s & 1, r = (s >> 1) & 3, l = s >> 3;
    const int SRCT[4] = {0, 1, 1, 1};
    const int st = SRCT[r];
    const float* W = (kv ? Wv : Wk) + ((long)l * T_ + st) * H_ * H_;
    const float* A = (kv ? m_rel : a_rel) + ((long)l * R_ + r) * HEADS_ * D_ * D_;
    const int hh = blockIdx.y, kt = blockIdx.x;
    __shared__ float As[32][33];
    __shared__ float Ws[64][33];
    const int tid = threadIdx.x;
    {
        int d = tid >> 3, e4 = (tid & 7) * 4;
        float4 v = *(const float4*)(A + (hh * D_ + d) * D_ + e4);
        As[d][e4] = v.x; As[d][e4 + 1] = v.y; As[d][e4 + 2] = v.z; As[d][e4 + 3] = v.w;
    }
    #pragma unroll
    for (int p = 0; p < 2; ++p) {
        int idx = p * 256 + tid;
        int row = idx >> 3, c4 = (idx & 7) * 4;
        float4 v = *(const float4*)(W + (long)(kt * 64 + row) * H_ + hh * 32 + c4);
        Ws[row][c4] = v.x; Ws[row][c4 + 1] = v.y; Ws[row][c4 + 2] = v.z; Ws[row][c4 + 3] = v.w;
    }
    __syncthreads();
    const int kl = tid & 63, eb = tid >> 6;
    #pragma unroll
    for (int ii = 0; ii < 8; ++ii) {
        int e = eb * 8 + ii;
        float acc = 0.f;
        #pragma unroll
        for (int d = 0; d < 32; ++d)
            acc += As[d][e] * Ws[kl][d];
        long rowIdx = (long)(s >> 1) * 512 + (kv * 256) + hh * 32 + e;
        WkvT[rowIdx * H_ + kt * 64 + kl] = f2bf(acc);
    }
}

__global__ void fuse_b_kernel(
    const float* __restrict__ bk, const float* __restrict__ bv,
    const float* __restrict__ a_rel, const float* __restrict__ m_rel,
    float* __restrict__ bkv)
{
    const int s = blockIdx.x;
    const int kv = s & 1, r = (s >> 1) & 3, l = s >> 3;
    const int SRCT[4] = {0, 1, 1, 1};
    const int st = SRCT[r];
    const float* b = (kv ? bv : bk) + ((long)l * T_ + st) * H_;
    const float* A = (kv ? m_rel : a_rel) + ((long)l * R_ + r) * HEADS_ * D_ * D_;
    const int tid = threadIdx.x;
    const int hh = tid >> 5, e = tid & 31;
    float acc = 0.f;
    #pragma unroll
    for (int d = 0; d < D_; ++d)
        acc += b[hh * D_ + d] * A[(hh * D_ + d) * D_ + e];
    bkv[(long)(s >> 1) * 512 + kv * 256 + tid] = acc;
}

// ---------------- CSR build (parallel scan) ----------------
__global__ void hist_kernel(const int* __restrict__ ei, int* __restrict__ indeg,
                            int Nn, int E)
{
    int idx = blockIdx.x * 256 + threadIdx.x;
    if (idx >= R_ * E) return;
    int r = idx / E, e = idx - r * E;
    int d = ei[(size_t)r * 2 * E + E + e];
    atomicAdd(indeg + (size_t)r * Nn + d, 1);
}

// per-chunk totals: grid (nch, R)
__global__ __launch_bounds__(256) void csr_part_kernel(
    const int* __restrict__ indeg, int* __restrict__ partials, int Nn, int nch)
{
    const int r = blockIdx.y, c = blockIdx.x, tid = threadIdx.x;
    const int lane = tid & 63, wave = tid >> 6;
    int idx = c * 256 + tid;
    int v = (idx < Nn) ? indeg[(size_t)r * Nn + idx] : 0;
    #pragma unroll
    for (int off = 1; off < 64; off <<= 1) v += __shfl_xor(v, off);
    __shared__ int wsum[4];
    if (lane == 0) wsum[wave] = v;
    __syncthreads();
    if (tid == 0) partials[r * nch + c] = wsum[0] + wsum[1] + wsum[2] + wsum[3];
}

// exclusive scan of partials: grid (R), nch <= 256
__global__ __launch_bounds__(256) void csr_scanpart_kernel(
    int* __restrict__ partials, int nch)
{
    const int r = blockIdx.x, tid = threadIdx.x;
    __shared__ int sh[256];
    int v = (tid < nch) ? partials[r * nch + tid] : 0;
    sh[tid] = v;
    __syncthreads();
    for (int off = 1; off < 256; off <<= 1) {
        int u = (tid >= off) ? sh[tid - off] : 0;
        __syncthreads();
        sh[tid] += u;
        __syncthreads();
    }
    if (tid < nch) partials[r * nch + tid] = sh[tid] - v;   // exclusive
}

// per-chunk scan + base -> offs & cursor: grid (nch, R)
__global__ __launch_bounds__(256) void csr_write_kernel(
    const int* __restrict__ indeg, const int* __restrict__ partials,
    int* __restrict__ offs, int* __restrict__ cursor, int Nn, int nch)
{
    const int r = blockIdx.y, c = blockIdx.x, tid = threadIdx.x;
    int idx = c * 256 + tid;
    int v = (idx < Nn) ? indeg[(size_t)r * Nn + idx] : 0;
    __shared__ int sh[256];
    sh[tid] = v;
    __syncthreads();
    for (int off = 1; off < 256; off <<= 1) {
        int u = (tid >= off) ? sh[tid - off] : 0;
        __syncthreads();
        sh[tid] += u;
        __syncthreads();
    }
    int incl = sh[tid];
    int base = partials[r * nch + c];
    if (idx < Nn) {
        int excl = base + incl - v;
        offs[(size_t)r * (Nn + 1) + idx] = excl;
        cursor[(size_t)r * Nn + idx] = excl;
        if (idx == Nn - 1) offs[(size_t)r * (Nn + 1) + Nn] = base + incl;
    }
}

__global__ void scatter_kernel(const int* __restrict__ ei, int* __restrict__ cursor,
                               int* __restrict__ esrc, int Nn, int E)
{
    int idx = blockIdx.x * 256 + threadIdx.x;
    if (idx >= R_ * E) return;
    int r = idx / E, e = idx - r * E;
    int s = ei[(size_t)r * 2 * E + e];
    int d = ei[(size_t)r * 2 * E + E + e];
    int pos = atomicAdd(cursor + (size_t)r * Nn + d, 1);
    esrc[(size_t)r * E + pos] = s;
}

// ---------------- batched per-node attention aggregation ----------------
// grid (ceil(N/4), 3): blockIdx.y = destination-type group.
// Per-relation INDEPENDENT softmax; normalized results summed (matches ref).
// KV layout: [r][N][512] bf16 = k(256) | v(256) interleaved per node.
// In-place: wave reads q row d of its dt, writes agg row d of same slot.
__global__ __launch_bounds__(256) void agg_all_kernel(
    const int* __restrict__ offs, const int* __restrict__ esrc,
    bf16_t* __restrict__ qbuf, const bf16_t* __restrict__ KV,
    const float* __restrict__ p_l,   // p_rel + l*R*HEADS
    float scale, int Nn, int E)
{
    static const int NRELg[3] = {2, 1, 1};
    static const int R0g[3]  = {0, 1, 3};
    static const int R1g[3]  = {2, 0, 0};
    static const int DTg[3]  = {1, 0, 2};
    const int grp = blockIdx.y;
    const int wave = threadIdx.x >> 6, lane = threadIdx.x & 63;
    const int d = blockIdx.x * 4 + wave;
    if (d >= Nn) return;
    const int head = lane >> 3;
    const int dt = DTg[grp], nrel = NRELg[grp];

    bf16_t* qrow = qbuf + (size_t)dt * Nn * H_ + (size_t)d * H_;
    ushort4 qu = ((const ushort4*)qrow)[lane];
    float q0 = bf2f(qu.x), q1 = bf2f(qu.y), q2 = bf2f(qu.z), q3 = bf2f(qu.w);

    float t0 = 0.f, t1 = 0.f, t2 = 0.f, t3 = 0.f;
    for (int rr = 0; rr < nrel; ++rr) {
        const int r = rr ? R1g[grp] : R0g[grp];
        const int* of = offs + (size_t)r * (Nn + 1);
        const int* es = esrc + (size_t)r * E;
        const bf16_t* KVr = KV + (size_t)r * Nn * 512;
        const float pr = p_l[r * HEADS_ + head] * scale;
        float m = -INFINITY, s = 0.f;
        float a0 = 0.f, a1 = 0.f, a2 = 0.f, a3 = 0.f;
        int beg = of[d], end = of[d + 1];
        for (int e = beg; e < end; ++e) {
            int si = es[e];
            const bf16_t* row = KVr + (size_t)si * 512;
            ushort4 ku = ((const ushort4*)row)[lane];
            ushort4 vu = ((const ushort4*)(row + 256))[lane];
            float dt_ = q0 * bf2f(ku.x) + q1 * bf2f(ku.y) + q2 * bf2f(ku.z) + q3 * bf2f(ku.w);
            dt_ += __shfl_xor(dt_, 1);
            dt_ += __shfl_xor(dt_, 2);
            dt_ += __shfl_xor(dt_, 4);
            float lg = dt_ * pr;
            float mnew = fmaxf(m, lg);
            float fac = __expf(m - mnew);
            float p = __expf(lg - mnew);
            s = s * fac + p;
            a0 = a0 * fac + p * bf2f(vu.x);
            a1 = a1 * fac + p * bf2f(vu.y);
            a2 = a2 * fac + p * bf2f(vu.z);
            a3 = a3 * fac + p * bf2f(vu.w);
            m = mnew;
        }
        float invs = (s > 0.f) ? 1.f / s : 0.f;
        t0 += a0 * invs; t1 += a1 * invs; t2 += a2 * invs; t3 += a3 * invs;
    }
    ushort4 ou;
    ou.x = f2bf(gelu_exact(t0));
    ou.y = f2bf(gelu_exact(t1));
    ou.z = f2bf(gelu_exact(t2));
    ou.w = f2bf(gelu_exact(t3));
    ((ushort4*)qrow)[lane] = ou;
}

// ---------------- MFMA bf16 GEMM (TA = bf16 or fp32-with-convert) ----------------
// C[M,Nc] = actC( A[M,K] @ BT[Nc,K]^T + bias[Nc] ), batched over blockIdx.z.
template<typename TA, typename TC, int ACT_C>
__global__ __launch_bounds__(256) void mfma_gemm(
    const TA* __restrict__ A, const bf16_t* __restrict__ BT,
    const float* __restrict__ bias, TC* __restrict__ C,
    int M, int K, int Nc,
    long strideA, long strideB, long strideBias, long strideC)
{
    const TA* Ab = A + (long)blockIdx.z * strideA;
    const bf16_t* Bb = BT + (long)blockIdx.z * strideB;
    const float* biasb = bias + (long)blockIdx.z * strideBias;
    TC* Cb = C + (long)blockIdx.z * strideC;

    __shared__ bf16_t As[128 * 32];
    __shared__ bf16_t Bs[128 * 32];
    const int tid = threadIdx.x;
    const int lane = tid & 63, wave = tid >> 6;
    const int wr = wave >> 1, wc = wave & 1;
    const int bm = blockIdx.y * 128, bn = blockIdx.x * 128;
    const int r16 = lane & 15, g = lane >> 4;
    f32x4 acc[4][4] = {};

    for (int k0 = 0; k0 < K; k0 += 32) {
        #pragma unroll
        for (int p = 0; p < 2; ++p) {
            int idx = p * 256 + tid;
            int row = idx >> 2, seg = idx & 3;
            int grow = bm + row;
            bf16x8 av = {};
            if (grow < M) {
                if constexpr (sizeof(TA) == 2) {
                    av = *(const bf16x8*)(Ab + (long)grow * K + k0 + seg * 8);
                } else {
                    const float* sp = (const float*)Ab + (long)grow * K + k0 + seg * 8;
                    float4 f0 = *(const float4*)sp, f1 = *(const float4*)(sp + 4);
                    av[0] = (short)f2bf(f0.x); av[1] = (short)f2bf(f0.y);
                    av[2] = (short)f2bf(f0.z); av[3] = (short)f2bf(f0.w);
                    av[4] = (short)f2bf(f1.x); av[5] = (short)f2bf(f1.y);
                    av[6] = (short)f2bf(f1.z); av[7] = (short)f2bf(f1.w);
                }
            }
            *(bf16x8*)(As + row * 32 + seg * 8) = av;
            bf16x8 bv = *(const bf16x8*)(Bb + (long)(bn + row) * K + k0 + seg * 8);
            *(bf16x8*)(Bs + row * 32 + seg * 8) = bv;
        }
        __syncthreads();
        bf16x8 af[4], bfr[4];
        #pragma unroll
        for (int m = 0; m < 4; ++m)
            af[m] = *(const bf16x8*)(As + (wr * 64 + m * 16 + r16) * 32 + g * 8);
        #pragma unroll
        for (int n = 0; n < 4; ++n)
            bfr[n] = *(const bf16x8*)(Bs + (wc * 64 + n * 16 + r16) * 32 + g * 8);
        #pragma unroll
        for (int m = 0; m < 4; ++m)
            #pragma unroll
            for (int n = 0; n < 4; ++n)
                acc[m][n] = __builtin_amdgcn_mfma_f32_16x16x32_bf16(af[m], bfr[n], acc[m][n], 0, 0, 0);
        __syncthreads();
    }

    #pragma unroll
    for (int n = 0; n < 4; ++n) {
        int col = bn + wc * 64 + n * 16 + r16;
        float bb = biasb[col];
        #pragma unroll
        for (int m = 0; m < 4; ++m) {
            int rowbase = bm + wr * 64 + m * 16 + g * 4;
            #pragma unroll
            for (int j = 0; j < 4; ++j) {
                int row = rowbase + j;
                if (row < M) {
                    float vv = acc[m][n][j] + bb;
                    if (ACT_C) vv = fmaxf(vv, 0.f);
                    if constexpr (sizeof(TC) == 4)
                        Cb[(long)row * Nc + col] = vv;
                    else
                        Cb[(long)row * Nc + col] = f2bf(vv);
                }
            }
        }
    }
}

// ---------------- fused skip-gate + residual + LN + ReLU ----------------
// o is contiguous [T*N][H] (obuf), h is [T*N][H]
__global__ __launch_bounds__(256) void skip_ln_kernel(
    bf16_t* __restrict__ h, const bf16_t* __restrict__ o,
    const float* __restrict__ skip, const float* __restrict__ ln_g,
    const float* __restrict__ ln_b, int Nn)
{
    const int wave = threadIdx.x >> 6;
    const int lane = threadIdx.x & 63;
    long row = (long)blockIdx.x * 4 + wave;
    long total = (long)T_ * Nn;
    if (row >= total) return;
    int t = (int)(row / Nn);
    float beta = 1.f / (1.f + expf(-skip[t]));
    float cb = 2.f - beta;
    ushort4 hv = reinterpret_cast<const ushort4*>(h + row * H_)[lane];
    ushort4 ov = reinterpret_cast<const ushort4*>(o + row * H_)[lane];
    float u0 = beta * bf2f(ov.x) + cb * bf2f(hv.x);
    float u1 = beta * bf2f(ov.y) + cb * bf2f(hv.y);
    float u2 = beta * bf2f(ov.z) + cb * bf2f(hv.z);
    float u3 = beta * bf2f(ov.w) + cb * bf2f(hv.w);
    float s1 = u0 + u1 + u2 + u3;
    float s2 = u0 * u0 + u1 * u1 + u2 * u2 + u3 * u3;
    #pragma unroll
    for (int off = 1; off < 64; off <<= 1) {
        s1 += __shfl_xor(s1, off);
        s2 += __shfl_xor(s2, off);
    }
    float mu = s1 * (1.f / H_);
    float var = s2 * (1.f / H_) - mu * mu;
    float inv = rsqrtf(var + 1e-5f);
    const float4 g = reinterpret_cast<const float4*>(ln_g + (size_t)t * H_)[lane];
    const float4 b = reinterpret_cast<const float4*>(ln_b + (size_t)t * H_)[lane];
    ushort4 r;
    r.x = f2bf(fmaxf((u0 - mu) * inv * g.x + b.x, 0.f));
    r.y = f2bf(fmaxf((u1 - mu) * inv * g.y + b.y, 0.f));
    r.z = f2bf(fmaxf((u2 - mu) * inv * g.z + b.z, 0.f));
    r.w = f2bf(fmaxf((u3 - mu) * inv * g.w + b.w, 0.f));
    reinterpret_cast<ushort4*>(h + row * H_)[lane] = r;
}

// ---------------- host side ----------------
extern "C" void kernel_launch(void* const* d_in, const int* in_sizes, int n_in,
                              void* d_out, int out_size, void* d_ws, size_t ws_size,
                              hipStream_t stream)
{
    const float* x     = (const float*)d_in[0];
    const int*   ei    = (const int*)  d_in[1];
    const float* Win   = (const float*)d_in[2];
    const float* b_in  = (const float*)d_in[3];
    const float* Wk    = (const float*)d_in[4];
    const float* bk    = (const float*)d_in[5];
    const float* Wq    = (const float*)d_in[6];
    const float* bq    = (const float*)d_in[7];
    const float* Wv    = (const float*)d_in[8];
    const float* bv    = (const float*)d_in[9];
    const float* Wa    = (const float*)d_in[10];
    const float* ba    = (const float*)d_in[11];
    const float* skip  = (const float*)d_in[12];
    const float* a_rel = (const float*)d_in[13];
    const float* m_rel = (const float*)d_in[14];
    const float* p_rel = (const float*)d_in[15];
    const float* ln_g  = (const float*)d_in[16];
    const float* ln_b  = (const float*)d_in[17];
    const float* Wout  = (const float*)d_in[18];
    const float* bout  = (const float*)d_in[19];
    float* out = (float*)d_out;

    const int N = in_sizes[0] / (T_ * FIN_);
    const int E = in_sizes[1] / (R_ * 2);
    const size_t NH = (size_t)N * H_;
    const int nch = (N + 255) / 256;   // <= 256 assumed (N <= 65536)

    char* wp = (char*)d_ws;
    auto alloc = [&](size_t bytes) {
        void* r = wp;
        wp += (bytes + 255) & ~(size_t)255;
        return r;
    };
    bf16_t* h     = (bf16_t*)alloc(T_ * NH * 2);          // 30.7 MB
    bf16_t* qbuf  = (bf16_t*)alloc(T_ * NH * 2);          // 30.7 MB (q -> agg in place)
    bf16_t* KV    = (bf16_t*)alloc((size_t)R_ * N * 512 * 2);   // 41 MB; obuf aliases
    int*    indeg = (int*)   alloc((size_t)R_ * N * 4);
    int*    offs  = (int*)   alloc((size_t)R_ * (N + 1) * 4);
    int*    cursor= (int*)   alloc((size_t)R_ * N * 4);
    int*    esrc  = (int*)   alloc((size_t)R_ * E * 4);
    int*    parts = (int*)   alloc((size_t)R_ * 256 * 4);
    bf16_t* WqT   = (bf16_t*)alloc((size_t)L_ * T_ * H_ * H_ * 2);
    bf16_t* WaT   = (bf16_t*)alloc((size_t)L_ * T_ * H_ * H_ * 2);
    bf16_t* WinT  = (bf16_t*)alloc((size_t)T_ * FIN_ * H_ * 2);
    bf16_t* WoutT = (bf16_t*)alloc((size_t)H_ * OUT_ * 2);
    bf16_t* WkvT  = (bf16_t*)alloc((size_t)L_ * R_ * 512 * H_ * 2);
    float*  bkv   = (float*) alloc((size_t)L_ * R_ * 512 * 4);

    bf16_t* obuf = KV;   // [3][N][256] reuse of KV after agg consumes it

    if ((size_t)(wp - (char*)d_ws) > ws_size) return;   // clean-fail guard

    const float scale = 0.17677669529663688f;  // 1/sqrt(32)
    dim3 blk(256);
    auto gM = [](long M) { return (int)((M + 127) / 128); };

    // ---- weight preprocessing ----
    transconv_kernel<<<dim3(4, 4, L_ * T_), blk, 0, stream>>>(Wq, WqT, H_, H_);
    transconv_kernel<<<dim3(4, 4, L_ * T_), blk, 0, stream>>>(Wa, WaT, H_, H_);
    transconv_kernel<<<dim3(4, 2, T_),      blk, 0, stream>>>(Win, WinT, FIN_, H_);
    transconv_kernel<<<dim3(2, 4, 1),       blk, 0, stream>>>(Wout, WoutT, H_, OUT_);
    fuse_wT_kernel<<<dim3(4, 8, 16), blk, 0, stream>>>(Wk, Wv, a_rel, m_rel, WkvT);
    fuse_b_kernel<<<16, blk, 0, stream>>>(bk, bv, a_rel, m_rel, bkv);

    // ---- CSR build (parallel) ----
    zero_kernel<<<256, blk, 0, stream>>>((unsigned*)indeg, (long)R_ * N);
    hist_kernel<<<(R_ * E + 255) / 256, blk, 0, stream>>>(ei, indeg, N, E);
    csr_part_kernel<<<dim3(nch, R_), blk, 0, stream>>>(indeg, parts, N, nch);
    csr_scanpart_kernel<<<R_, blk, 0, stream>>>(parts, nch);
    csr_write_kernel<<<dim3(nch, R_), blk, 0, stream>>>(indeg, parts, offs, cursor, N, nch);
    scatter_kernel<<<(R_ * E + 255) / 256, blk, 0, stream>>>(ei, cursor, esrc, N, E);

    // ---- input projection + relu (fp32 A converted in-GEMM) ----
    mfma_gemm<float, bf16_t, 1><<<dim3(H_ / 128, gM(N), T_), blk, 0, stream>>>(
        x, WinT, b_in, h, N, FIN_, H_,
        (long)N * FIN_, (long)FIN_ * H_, H_, (long)NH);

    for (int l = 0; l < L_; ++l) {
        const long lw = (long)l * R_;
        // KV for r0 (src type 0): one GEMM N x 512 x 256
        mfma_gemm<bf16_t, bf16_t, 0><<<dim3(512 / 128, gM(N), 1), blk, 0, stream>>>(
            h, WkvT + lw * 512 * H_, bkv + lw * 512, KV,
            N, H_, 512, 0L, 0L, 0L, 0L);
        // KV for r1..r3 (all src type 1): z=3, strideA=0
        mfma_gemm<bf16_t, bf16_t, 0><<<dim3(512 / 128, gM(N), 3), blk, 0, stream>>>(
            h + NH, WkvT + (lw + 1) * 512 * H_, bkv + (lw + 1) * 512, KV + (size_t)N * 512,
            N, H_, 512, 0L, 512L * H_, 512L, (long)N * 512);
        // q for all 3 node types: z=3
        mfma_gemm<bf16_t, bf16_t, 0><<<dim3(H_ / 128, gM(N), 3), blk, 0, stream>>>(
            h, WqT + (size_t)l * T_ * H_ * H_, bq + (size_t)l * T_ * H_, qbuf,
            N, H_, H_, (long)NH, (long)H_ * H_, (long)H_, (long)NH);
        // batched per-node per-relation softmax aggregation + GELU (in place in qbuf)
        agg_all_kernel<<<dim3((N + 3) / 4, 3), blk, 0, stream>>>(
            offs, esrc, qbuf, KV, p_rel + (size_t)l * R_ * HEADS_, scale, N, E);
        // o[t] = aggb[t] @ Wa[t] + ba[t] : z=3 (writes obuf = KV region)
        mfma_gemm<bf16_t, bf16_t, 0><<<dim3(H_ / 128, gM(N), 3), blk, 0, stream>>>(
            qbuf, WaT + (size_t)l * T_ * H_ * H_, ba + (size_t)l * T_ * H_, obuf,
            N, H_, H_, (long)NH, (long)H_ * H_, (long)H_, (long)NH);
        // skip-gate + residual + LN + ReLU
        skip_ln_kernel<<<((size_t)T_ * N + 3) / 4, blk, 0, stream>>>(
            h, obuf, skip + l * T_, ln_g + (size_t)l * T_ * H_, ln_b + (size_t)l * T_ * H_, N);
    }

    // shared output projection: h bf16 -> out fp32
    mfma_gemm<bf16_t, float, 0><<<dim3(OUT_ / 128, gM((long)T_ * N), 1), blk, 0, stream>>>(
        h, WoutT, bout, out, T_ * N, H_, OUT_, 0L, 0L, 0L, 0L);
}

// Round 7
// 425.248 us; speedup vs baseline: 4.6205x; 1.3303x over previous
//
#include <hip/hip_runtime.h>
#include <math.h>

// ---------------- constants from the reference ----------------
#define T_ 3
#define R_ 4
#define L_ 2
#define H_ 256
#define HEADS_ 8
#define D_ 32
#define FIN_ 128
#define OUT_ 128

typedef unsigned short bf16_t;
typedef __attribute__((ext_vector_type(8))) short bf16x8;
typedef __attribute__((ext_vector_type(4))) float f32x4;

__device__ __forceinline__ float bf2f(bf16_t h) {
    return __uint_as_float(((unsigned)h) << 16);
}
__device__ __forceinline__ bf16_t f2bf(float f) {
    unsigned u = __float_as_uint(f);
    u += 0x7FFFu + ((u >> 16) & 1u);          // round-to-nearest-even
    return (bf16_t)(u >> 16);
}
__device__ __forceinline__ float gelu_exact(float x) {
    return 0.5f * x * (1.0f + erff(x * 0.70710678118654752440f));
}

// ---------------- zero fill ----------------
__global__ void zero_kernel(unsigned* __restrict__ p, long n) {
    long i = (long)blockIdx.x * blockDim.x + threadIdx.x;
    long stride = (long)gridDim.x * blockDim.x;
    for (; i < n; i += stride) p[i] = 0u;
}

// ---------------- batched transpose+convert: [S][Rr][Cc] f32 -> [S][Cc][Rr] bf16 ----------------
__global__ __launch_bounds__(256) void transconv_kernel(
    const float* __restrict__ in, bf16_t* __restrict__ out, int Rr, int Cc)
{
    __shared__ float Ls[64][65];
    const int tid = threadIdx.x;
    const long base = (long)blockIdx.z * Rr * Cc;
    const int r0 = blockIdx.y * 64, c0 = blockIdx.x * 64;
    #pragma unroll
    for (int i = 0; i < 16; ++i) {
        int e = tid + i * 256; int row = e >> 6, col = e & 63;
        Ls[row][col] = in[base + (long)(r0 + row) * Cc + c0 + col];
    }
    __syncthreads();
    #pragma unroll
    for (int i = 0; i < 16; ++i) {
        int e = tid + i * 256; int row = e >> 6, col = e & 63;
        out[base + (long)(c0 + row) * Rr + r0 + col] = f2bf(Ls[col][row]);
    }
}

// ---------------- fused relation weights -> [l][r][kv*256+col][k] bf16 ----------------
__global__ __launch_bounds__(256) void fuse_wT_kernel(
    const float* __restrict__ Wk, const float* __restrict__ Wv,
    const float* __restrict__ a_rel, const float* __restrict__ m_rel,
    bf16_t* __restrict__ WkvT)
{
    const int s = blockIdx.z;
    const int kv = s & 1, r = (s >> 1) & 3, l = s >> 3;
    const int SRCT[4] = {0, 1, 1, 1};
    const int st = SRCT[r];
    const float* W = (kv ? Wv : Wk) + ((long)l * T_ + st) * H_ * H_;
    const float* A = (kv ? m_rel : a_rel) + ((long)l * R_ + r) * HEADS_ * D_ * D_;
    const int hh = blockIdx.y, kt = blockIdx.x;
    __shared__ float As[32][33];
    __shared__ float Ws[64][33];
    const int tid = threadIdx.x;
    {
        int d = tid >> 3, e4 = (tid & 7) * 4;
        float4 v = *(const float4*)(A + (hh * D_ + d) * D_ + e4);
        As[d][e4] = v.x; As[d][e4 + 1] = v.y; As[d][e4 + 2] = v.z; As[d][e4 + 3] = v.w;
    }
    #pragma unroll
    for (int p = 0; p < 2; ++p) {
        int idx = p * 256 + tid;
        int row = idx >> 3, c4 = (idx & 7) * 4;
        float4 v = *(const float4*)(W + (long)(kt * 64 + row) * H_ + hh * 32 + c4);
        Ws[row][c4] = v.x; Ws[row][c4 + 1] = v.y; Ws[row][c4 + 2] = v.z; Ws[row][c4 + 3] = v.w;
    }
    __syncthreads();
    const int kl = tid & 63, eb = tid >> 6;
    #pragma unroll
    for (int ii = 0; ii < 8; ++ii) {
        int e = eb * 8 + ii;
        float acc = 0.f;
        #pragma unroll
        for (int d = 0; d < 32; ++d)
            acc += As[d][e] * Ws[kl][d];
        long rowIdx = (long)(s >> 1) * 512 + (kv * 256) + hh * 32 + e;
        WkvT[rowIdx * H_ + kt * 64 + kl] = f2bf(acc);
    }
}

__global__ void fuse_b_kernel(
    const float* __restrict__ bk, const float* __restrict__ bv,
    const float* __restrict__ a_rel, const float* __restrict__ m_rel,
    float* __restrict__ bkv)
{
    const int s = blockIdx.x;
    const int kv = s & 1, r = (s >> 1) & 3, l = s >> 3;
    const int SRCT[4] = {0, 1, 1, 1};
    const int st = SRCT[r];
    const float* b = (kv ? bv : bk) + ((long)l * T_ + st) * H_;
    const float* A = (kv ? m_rel : a_rel) + ((long)l * R_ + r) * HEADS_ * D_ * D_;
    const int tid = threadIdx.x;
    const int hh = tid >> 5, e = tid & 31;
    float acc = 0.f;
    #pragma unroll
    for (int d = 0; d < D_; ++d)
        acc += b[hh * D_ + d] * A[(hh * D_ + d) * D_ + e];
    bkv[(long)(s >> 1) * 512 + kv * 256 + tid] = acc;
}

// ---------------- CSR build (parallel scan) ----------------
__global__ void hist_kernel(const int* __restrict__ ei, int* __restrict__ indeg,
                            int Nn, int E)
{
    int idx = blockIdx.x * 256 + threadIdx.x;
    if (idx >= R_ * E) return;
    int r = idx / E, e = idx - r * E;
    int d = ei[(size_t)r * 2 * E + E + e];
    atomicAdd(indeg + (size_t)r * Nn + d, 1);
}

__global__ __launch_bounds__(256) void csr_part_kernel(
    const int* __restrict__ indeg, int* __restrict__ partials, int Nn, int nch)
{
    const int r = blockIdx.y, c = blockIdx.x, tid = threadIdx.x;
    const int lane = tid & 63, wave = tid >> 6;
    int idx = c * 256 + tid;
    int v = (idx < Nn) ? indeg[(size_t)r * Nn + idx] : 0;
    #pragma unroll
    for (int off = 1; off < 64; off <<= 1) v += __shfl_xor(v, off);
    __shared__ int wsum[4];
    if (lane == 0) wsum[wave] = v;
    __syncthreads();
    if (tid == 0) partials[r * nch + c] = wsum[0] + wsum[1] + wsum[2] + wsum[3];
}

__global__ __launch_bounds__(256) void csr_scanpart_kernel(
    int* __restrict__ partials, int nch)
{
    const int r = blockIdx.x, tid = threadIdx.x;
    __shared__ int sh[256];
    int v = (tid < nch) ? partials[r * nch + tid] : 0;
    sh[tid] = v;
    __syncthreads();
    for (int off = 1; off < 256; off <<= 1) {
        int u = (tid >= off) ? sh[tid - off] : 0;
        __syncthreads();
        sh[tid] += u;
        __syncthreads();
    }
    if (tid < nch) partials[r * nch + tid] = sh[tid] - v;   // exclusive
}

__global__ __launch_bounds__(256) void csr_write_kernel(
    const int* __restrict__ indeg, const int* __restrict__ partials,
    int* __restrict__ offs, int* __restrict__ cursor, int Nn, int nch)
{
    const int r = blockIdx.y, c = blockIdx.x, tid = threadIdx.x;
    int idx = c * 256 + tid;
    int v = (idx < Nn) ? indeg[(size_t)r * Nn + idx] : 0;
    __shared__ int sh[256];
    sh[tid] = v;
    __syncthreads();
    for (int off = 1; off < 256; off <<= 1) {
        int u = (tid >= off) ? sh[tid - off] : 0;
        __syncthreads();
        sh[tid] += u;
        __syncthreads();
    }
    int incl = sh[tid];
    int base = partials[r * nch + c];
    if (idx < Nn) {
        int excl = base + incl - v;
        offs[(size_t)r * (Nn + 1) + idx] = excl;
        cursor[(size_t)r * Nn + idx] = excl;
        if (idx == Nn - 1) offs[(size_t)r * (Nn + 1) + Nn] = base + incl;
    }
}

__global__ void scatter_kernel(const int* __restrict__ ei, int* __restrict__ cursor,
                               int* __restrict__ esrc, int Nn, int E)
{
    int idx = blockIdx.x * 256 + threadIdx.x;
    if (idx >= R_ * E) return;
    int r = idx / E, e = idx - r * E;
    int s = ei[(size_t)r * 2 * E + e];
    int d = ei[(size_t)r * 2 * E + E + e];
    int pos = atomicAdd(cursor + (size_t)r * Nn + d, 1);
    esrc[(size_t)r * E + pos] = s;
}

// ---------------- batched per-node attention aggregation ----------------
__global__ __launch_bounds__(256) void agg_all_kernel(
    const int* __restrict__ offs, const int* __restrict__ esrc,
    bf16_t* __restrict__ qbuf, const bf16_t* __restrict__ KV,
    const float* __restrict__ p_l,   // p_rel + l*R*HEADS
    float scale, int Nn, int E)
{
    static const int NRELg[3] = {2, 1, 1};
    static const int R0g[3]  = {0, 1, 3};
    static const int R1g[3]  = {2, 0, 0};
    static const int DTg[3]  = {1, 0, 2};
    const int grp = blockIdx.y;
    const int wave = threadIdx.x >> 6, lane = threadIdx.x & 63;
    const int d = blockIdx.x * 4 + wave;
    if (d >= Nn) return;
    const int head = lane >> 3;
    const int dt = DTg[grp], nrel = NRELg[grp];

    bf16_t* qrow = qbuf + (size_t)dt * Nn * H_ + (size_t)d * H_;
    ushort4 qu = ((const ushort4*)qrow)[lane];
    float q0 = bf2f(qu.x), q1 = bf2f(qu.y), q2 = bf2f(qu.z), q3 = bf2f(qu.w);

    float t0 = 0.f, t1 = 0.f, t2 = 0.f, t3 = 0.f;
    for (int rr = 0; rr < nrel; ++rr) {
        const int r = rr ? R1g[grp] : R0g[grp];
        const int* of = offs + (size_t)r * (Nn + 1);
        const int* es = esrc + (size_t)r * E;
        const bf16_t* KVr = KV + (size_t)r * Nn * 512;
        const float pr = p_l[r * HEADS_ + head] * scale;
        float m = -INFINITY, s = 0.f;
        float a0 = 0.f, a1 = 0.f, a2 = 0.f, a3 = 0.f;
        int beg = of[d], end = of[d + 1];
        for (int e = beg; e < end; ++e) {
            int si = es[e];
            const bf16_t* row = KVr + (size_t)si * 512;
            ushort4 ku = ((const ushort4*)row)[lane];
            ushort4 vu = ((const ushort4*)(row + 256))[lane];
            float dt_ = q0 * bf2f(ku.x) + q1 * bf2f(ku.y) + q2 * bf2f(ku.z) + q3 * bf2f(ku.w);
            dt_ += __shfl_xor(dt_, 1);
            dt_ += __shfl_xor(dt_, 2);
            dt_ += __shfl_xor(dt_, 4);
            float lg = dt_ * pr;
            float mnew = fmaxf(m, lg);
            float fac = __expf(m - mnew);
            float p = __expf(lg - mnew);
            s = s * fac + p;
            a0 = a0 * fac + p * bf2f(vu.x);
            a1 = a1 * fac + p * bf2f(vu.y);
            a2 = a2 * fac + p * bf2f(vu.z);
            a3 = a3 * fac + p * bf2f(vu.w);
            m = mnew;
        }
        float invs = (s > 0.f) ? 1.f / s : 0.f;
        t0 += a0 * invs; t1 += a1 * invs; t2 += a2 * invs; t3 += a3 * invs;
    }
    ushort4 ou;
    ou.x = f2bf(gelu_exact(t0));
    ou.y = f2bf(gelu_exact(t1));
    ou.z = f2bf(gelu_exact(t2));
    ou.w = f2bf(gelu_exact(t3));
    ((ushort4*)qrow)[lane] = ou;
}

// ---------------- MFMA bf16 GEMM ----------------
// C[M,Nc] = actC( A[M,K] @ BT[Nc,K]^T + bias[Nc] ), batched over z.
// LDS padded to stride 40 (conflict-free frag reads); bf16 epilogue staged
// through LDS for coalesced 16B stores; XCD-chunked block swizzle.
#define ASTR 40
#define ESTR 72

template<typename TA, typename TC, int ACT_C>
__global__ __launch_bounds__(256) void mfma_gemm(
    const TA* __restrict__ A, const bf16_t* __restrict__ BT,
    const float* __restrict__ bias, TC* __restrict__ C,
    int M, int K, int Nc,
    long strideA, long strideB, long strideBias, long strideC)
{
    // bijective XCD-chunked swizzle: same-y blocks contiguous per XCD
    const int gX = gridDim.x, gY = gridDim.y, gZ = gridDim.z;
    const int nwg = gX * gY * gZ;
    {
    }
    int flat = blockIdx.x + gX * (blockIdx.y + gY * blockIdx.z);
    const int qch = nwg >> 3, rch = nwg & 7;
    int xcd = flat & 7, cidx = flat >> 3;
    int swz = (xcd < rch ? xcd * (qch + 1) : rch * (qch + 1) + (xcd - rch) * qch) + cidx;
    const int by = swz / (gX * gZ);
    int rem = swz - by * (gX * gZ);
    const int bz = rem / gX;
    const int bx = rem - bz * gX;

    const TA* Ab = A + (long)bz * strideA;
    const bf16_t* Bb = BT + (long)bz * strideB;
    const float* biasb = bias + (long)bz * strideBias;
    TC* Cb = C + (long)bz * strideC;

    __shared__ bf16_t As[128 * ASTR];
    __shared__ bf16_t Bs[128 * ASTR];
    __shared__ bf16_t Es[4 * 16 * ESTR];
    const int tid = threadIdx.x;
    const int lane = tid & 63, wave = tid >> 6;
    const int wr = wave >> 1, wc = wave & 1;
    const int bm = by * 128, bn = bx * 128;
    const int r16 = lane & 15, g = lane >> 4;
    f32x4 acc[4][4] = {};

    for (int k0 = 0; k0 < K; k0 += 32) {
        #pragma unroll
        for (int p = 0; p < 2; ++p) {
            int idx = p * 256 + tid;
            int row = idx >> 2, seg = idx & 3;
            int grow = bm + row;
            bf16x8 av = {};
            if (grow < M) {
                if constexpr (sizeof(TA) == 2) {
                    av = *(const bf16x8*)(Ab + (long)grow * K + k0 + seg * 8);
                } else {
                    const float* sp = (const float*)Ab + (long)grow * K + k0 + seg * 8;
                    float4 f0 = *(const float4*)sp, f1 = *(const float4*)(sp + 4);
                    av[0] = (short)f2bf(f0.x); av[1] = (short)f2bf(f0.y);
                    av[2] = (short)f2bf(f0.z); av[3] = (short)f2bf(f0.w);
                    av[4] = (short)f2bf(f1.x); av[5] = (short)f2bf(f1.y);
                    av[6] = (short)f2bf(f1.z); av[7] = (short)f2bf(f1.w);
                }
            }
            *(bf16x8*)(As + row * ASTR + seg * 8) = av;
            bf16x8 bv = *(const bf16x8*)(Bb + (long)(bn + row) * K + k0 + seg * 8);
            *(bf16x8*)(Bs + row * ASTR + seg * 8) = bv;
        }
        __syncthreads();
        bf16x8 af[4], bfr[4];
        #pragma unroll
        for (int m = 0; m < 4; ++m)
            af[m] = *(const bf16x8*)(As + (wr * 64 + m * 16 + r16) * ASTR + g * 8);
        #pragma unroll
        for (int n = 0; n < 4; ++n)
            bfr[n] = *(const bf16x8*)(Bs + (wc * 64 + n * 16 + r16) * ASTR + g * 8);
        #pragma unroll
        for (int m = 0; m < 4; ++m)
            #pragma unroll
            for (int n = 0; n < 4; ++n)
                acc[m][n] = __builtin_amdgcn_mfma_f32_16x16x32_bf16(af[m], bfr[n], acc[m][n], 0, 0, 0);
        __syncthreads();
    }

    float bb[4];
    #pragma unroll
    for (int n = 0; n < 4; ++n)
        bb[n] = biasb[bn + wc * 64 + n * 16 + r16];

    if constexpr (sizeof(TC) == 2) {
        // staged epilogue: wave-local LDS round-trip -> coalesced bf16x8 stores
        bf16_t* st = Es + wave * (16 * ESTR);
        #pragma unroll
        for (int m = 0; m < 4; ++m) {
            int rowbase = bm + wr * 64 + m * 16;
            #pragma unroll
            for (int n = 0; n < 4; ++n) {
                #pragma unroll
                for (int j = 0; j < 4; ++j) {
                    float vv = acc[m][n][j] + bb[n];
                    if (ACT_C) vv = fmaxf(vv, 0.f);
                    st[(g * 4 + j) * ESTR + n * 16 + r16] = f2bf(vv);
                }
            }
            #pragma unroll
            for (int p = 0; p < 2; ++p) {
                int row = p * 8 + (lane >> 3);
                int col0 = (lane & 7) * 8;
                int grow = rowbase + row;
                bf16x8 val = *(const bf16x8*)(st + row * ESTR + col0);
                if (grow < M)
                    *(bf16x8*)(Cb + (long)grow * Nc + bn + wc * 64 + col0) = val;
            }
        }
    } else {
        #pragma unroll
        for (int n = 0; n < 4; ++n) {
            int col = bn + wc * 64 + n * 16 + r16;
            #pragma unroll
            for (int m = 0; m < 4; ++m) {
                int rowbase = bm + wr * 64 + m * 16 + g * 4;
                #pragma unroll
                for (int j = 0; j < 4; ++j) {
                    int row = rowbase + j;
                    if (row < M) {
                        float vv = acc[m][n][j] + bb[n];
                        if (ACT_C) vv = fmaxf(vv, 0.f);
                        Cb[(long)row * Nc + col] = vv;
                    }
                }
            }
        }
    }
}

// ---------------- fused skip-gate + residual + LN + ReLU ----------------
__global__ __launch_bounds__(256) void skip_ln_kernel(
    bf16_t* __restrict__ h, const bf16_t* __restrict__ o,
    const float* __restrict__ skip, const float* __restrict__ ln_g,
    const float* __restrict__ ln_b, int Nn)
{
    const int wave = threadIdx.x >> 6;
    const int lane = threadIdx.x & 63;
    long row = (long)blockIdx.x * 4 + wave;
    long total = (long)T_ * Nn;
    if (row >= total) return;
    int t = (int)(row / Nn);
    float beta = 1.f / (1.f + expf(-skip[t]));
    float cb = 2.f - beta;
    ushort4 hv = reinterpret_cast<const ushort4*>(h + row * H_)[lane];
    ushort4 ov = reinterpret_cast<const ushort4*>(o + row * H_)[lane];
    float u0 = beta * bf2f(ov.x) + cb * bf2f(hv.x);
    float u1 = beta * bf2f(ov.y) + cb * bf2f(hv.y);
    float u2 = beta * bf2f(ov.z) + cb * bf2f(hv.z);
    float u3 = beta * bf2f(ov.w) + cb * bf2f(hv.w);
    float s1 = u0 + u1 + u2 + u3;
    float s2 = u0 * u0 + u1 * u1 + u2 * u2 + u3 * u3;
    #pragma unroll
    for (int off = 1; off < 64; off <<= 1) {
        s1 += __shfl_xor(s1, off);
        s2 += __shfl_xor(s2, off);
    }
    float mu = s1 * (1.f / H_);
    float var = s2 * (1.f / H_) - mu * mu;
    float inv = rsqrtf(var + 1e-5f);
    const float4 g = reinterpret_cast<const float4*>(ln_g + (size_t)t * H_)[lane];
    const float4 b = reinterpret_cast<const float4*>(ln_b + (size_t)t * H_)[lane];
    ushort4 r;
    r.x = f2bf(fmaxf((u0 - mu) * inv * g.x + b.x, 0.f));
    r.y = f2bf(fmaxf((u1 - mu) * inv * g.y + b.y, 0.f));
    r.z = f2bf(fmaxf((u2 - mu) * inv * g.z + b.z, 0.f));
    r.w = f2bf(fmaxf((u3 - mu) * inv * g.w + b.w, 0.f));
    reinterpret_cast<ushort4*>(h + row * H_)[lane] = r;
}

// ---------------- host side ----------------
extern "C" void kernel_launch(void* const* d_in, const int* in_sizes, int n_in,
                              void* d_out, int out_size, void* d_ws, size_t ws_size,
                              hipStream_t stream)
{
    const float* x     = (const float*)d_in[0];
    const int*   ei    = (const int*)  d_in[1];
    const float* Win   = (const float*)d_in[2];
    const float* b_in  = (const float*)d_in[3];
    const float* Wk    = (const float*)d_in[4];
    const float* bk    = (const float*)d_in[5];
    const float* Wq    = (const float*)d_in[6];
    const float* bq    = (const float*)d_in[7];
    const float* Wv    = (const float*)d_in[8];
    const float* bv    = (const float*)d_in[9];
    const float* Wa    = (const float*)d_in[10];
    const float* ba    = (const float*)d_in[11];
    const float* skip  = (const float*)d_in[12];
    const float* a_rel = (const float*)d_in[13];
    const float* m_rel = (const float*)d_in[14];
    const float* p_rel = (const float*)d_in[15];
    const float* ln_g  = (const float*)d_in[16];
    const float* ln_b  = (const float*)d_in[17];
    const float* Wout  = (const float*)d_in[18];
    const float* bout  = (const float*)d_in[19];
    float* out = (float*)d_out;

    const int N = in_sizes[0] / (T_ * FIN_);
    const int E = in_sizes[1] / (R_ * 2);
    const size_t NH = (size_t)N * H_;
    const int nch = (N + 255) / 256;

    char* wp = (char*)d_ws;
    auto alloc = [&](size_t bytes) {
        void* r = wp;
        wp += (bytes + 255) & ~(size_t)255;
        return r;
    };
    bf16_t* h     = (bf16_t*)alloc(T_ * NH * 2);
    bf16_t* qbuf  = (bf16_t*)alloc(T_ * NH * 2);
    bf16_t* KV    = (bf16_t*)alloc((size_t)R_ * N * 512 * 2);
    int*    indeg = (int*)   alloc((size_t)R_ * N * 4);
    int*    offs  = (int*)   alloc((size_t)R_ * (N + 1) * 4);
    int*    cursor= (int*)   alloc((size_t)R_ * N * 4);
    int*    esrc  = (int*)   alloc((size_t)R_ * E * 4);
    int*    parts = (int*)   alloc((size_t)R_ * 256 * 4);
    bf16_t* WqT   = (bf16_t*)alloc((size_t)L_ * T_ * H_ * H_ * 2);
    bf16_t* WaT   = (bf16_t*)alloc((size_t)L_ * T_ * H_ * H_ * 2);
    bf16_t* WinT  = (bf16_t*)alloc((size_t)T_ * FIN_ * H_ * 2);
    bf16_t* WoutT = (bf16_t*)alloc((size_t)H_ * OUT_ * 2);
    bf16_t* WkvT  = (bf16_t*)alloc((size_t)L_ * R_ * 512 * H_ * 2);
    float*  bkv   = (float*) alloc((size_t)L_ * R_ * 512 * 4);

    bf16_t* obuf = KV;   // reuse of KV after agg consumes it

    if ((size_t)(wp - (char*)d_ws) > ws_size) return;   // clean-fail guard

    const float scale = 0.17677669529663688f;  // 1/sqrt(32)
    dim3 blk(256);
    auto gM = [](long M) { return (int)((M + 127) / 128); };

    // ---- weight preprocessing ----
    transconv_kernel<<<dim3(4, 4, L_ * T_), blk, 0, stream>>>(Wq, WqT, H_, H_);
    transconv_kernel<<<dim3(4, 4, L_ * T_), blk, 0, stream>>>(Wa, WaT, H_, H_);
    transconv_kernel<<<dim3(4, 2, T_),      blk, 0, stream>>>(Win, WinT, FIN_, H_);
    transconv_kernel<<<dim3(2, 4, 1),       blk, 0, stream>>>(Wout, WoutT, H_, OUT_);
    fuse_wT_kernel<<<dim3(4, 8, 16), blk, 0, stream>>>(Wk, Wv, a_rel, m_rel, WkvT);
    fuse_b_kernel<<<16, blk, 0, stream>>>(bk, bv, a_rel, m_rel, bkv);

    // ---- CSR build (parallel) ----
    zero_kernel<<<256, blk, 0, stream>>>((unsigned*)indeg, (long)R_ * N);
    hist_kernel<<<(R_ * E + 255) / 256, blk, 0, stream>>>(ei, indeg, N, E);
    csr_part_kernel<<<dim3(nch, R_), blk, 0, stream>>>(indeg, parts, N, nch);
    csr_scanpart_kernel<<<R_, blk, 0, stream>>>(parts, nch);
    csr_write_kernel<<<dim3(nch, R_), blk, 0, stream>>>(indeg, parts, offs, cursor, N, nch);
    scatter_kernel<<<(R_ * E + 255) / 256, blk, 0, stream>>>(ei, cursor, esrc, N, E);

    // ---- input projection + relu ----
    mfma_gemm<float, bf16_t, 1><<<dim3(H_ / 128, gM(N), T_), blk, 0, stream>>>(
        x, WinT, b_in, h, N, FIN_, H_,
        (long)N * FIN_, (long)FIN_ * H_, H_, (long)NH);

    for (int l = 0; l < L_; ++l) {
        const long lw = (long)l * R_;
        // KV for r0 (src type 0)
        mfma_gemm<bf16_t, bf16_t, 0><<<dim3(512 / 128, gM(N), 1), blk, 0, stream>>>(
            h, WkvT + lw * 512 * H_, bkv + lw * 512, KV,
            N, H_, 512, 0L, 0L, 0L, 0L);
        // KV for r1..r3 (all src type 1): z=3, strideA=0
        mfma_gemm<bf16_t, bf16_t, 0><<<dim3(512 / 128, gM(N), 3), blk, 0, stream>>>(
            h + NH, WkvT + (lw + 1) * 512 * H_, bkv + (lw + 1) * 512, KV + (size_t)N * 512,
            N, H_, 512, 0L, 512L * H_, 512L, (long)N * 512);
        // q for all 3 node types: z=3
        mfma_gemm<bf16_t, bf16_t, 0><<<dim3(H_ / 128, gM(N), 3), blk, 0, stream>>>(
            h, WqT + (size_t)l * T_ * H_ * H_, bq + (size_t)l * T_ * H_, qbuf,
            N, H_, H_, (long)NH, (long)H_ * H_, (long)H_, (long)NH);
        // batched per-node per-relation softmax aggregation + GELU (in place)
        agg_all_kernel<<<dim3((N + 3) / 4, 3), blk, 0, stream>>>(
            offs, esrc, qbuf, KV, p_rel + (size_t)l * R_ * HEADS_, scale, N, E);
        // o[t] = aggb[t] @ Wa[t] + ba[t] : z=3
        mfma_gemm<bf16_t, bf16_t, 0><<<dim3(H_ / 128, gM(N), 3), blk, 0, stream>>>(
            qbuf, WaT + (size_t)l * T_ * H_ * H_, ba + (size_t)l * T_ * H_, obuf,
            N, H_, H_, (long)NH, (long)H_ * H_, (long)H_, (long)NH);
        // skip-gate + residual + LN + ReLU
        skip_ln_kernel<<<((size_t)T_ * N + 3) / 4, blk, 0, stream>>>(
            h, obuf, skip + l * T_, ln_g + (size_t)l * T_ * H_, ln_b + (size_t)l * T_ * H_, N);
    }

    // shared output projection: h bf16 -> out fp32
    mfma_gemm<bf16_t, float, 0><<<dim3(OUT_ / 128, gM((long)T_ * N), 1), blk, 0, stream>>>(
        h, WoutT, bout, out, T_ * N, H_, OUT_, 0L, 0L, 0L, 0L);
}

// Round 8
// 410.707 us; speedup vs baseline: 4.7841x; 1.0354x over previous
//
#include <hip/hip_runtime.h>
#include <math.h>

// ---------------- constants from the reference ----------------
#define T_ 3
#define R_ 4
#define L_ 2
#define H_ 256
#define HEADS_ 8
#define D_ 32
#define FIN_ 128
#define OUT_ 128

typedef unsigned short bf16_t;
typedef __attribute__((ext_vector_type(8))) short bf16x8;
typedef __attribute__((ext_vector_type(4))) float f32x4;

__device__ __forceinline__ float bf2f(bf16_t h) {
    return __uint_as_float(((unsigned)h) << 16);
}
__device__ __forceinline__ bf16_t f2bf(float f) {
    unsigned u = __float_as_uint(f);
    u += 0x7FFFu + ((u >> 16) & 1u);          // round-to-nearest-even
    return (bf16_t)(u >> 16);
}
__device__ __forceinline__ float gelu_exact(float x) {
    return 0.5f * x * (1.0f + erff(x * 0.70710678118654752440f));
}

// ---------------- zero fill ----------------
__global__ void zero_kernel(unsigned* __restrict__ p, long n) {
    long i = (long)blockIdx.x * blockDim.x + threadIdx.x;
    long stride = (long)gridDim.x * blockDim.x;
    for (; i < n; i += stride) p[i] = 0u;
}

// ---------------- dual transpose+convert: z<cnt0 -> (in0,out0) else (in1,out1) ----------------
// slices are [Rr][Cc] f32 -> [Cc][Rr] bf16, Rr=Cc=256 here (grid x=4,y=4)
__global__ __launch_bounds__(256) void transconv2_kernel(
    const float* __restrict__ in0, bf16_t* __restrict__ out0,
    const float* __restrict__ in1, bf16_t* __restrict__ out1,
    int cnt0, int Rr, int Cc)
{
    __shared__ float Ls[64][65];
    const int tid = threadIdx.x;
    int z = blockIdx.z;
    const float* in;
    bf16_t* out;
    if (z < cnt0) { in = in0; out = out0; }
    else          { in = in1; out = out1; z -= cnt0; }
    const long base = (long)z * Rr * Cc;
    const int r0 = blockIdx.y * 64, c0 = blockIdx.x * 64;
    #pragma unroll
    for (int i = 0; i < 16; ++i) {
        int e = tid + i * 256; int row = e >> 6, col = e & 63;
        Ls[row][col] = in[base + (long)(r0 + row) * Cc + c0 + col];
    }
    __syncthreads();
    #pragma unroll
    for (int i = 0; i < 16; ++i) {
        int e = tid + i * 256; int row = e >> 6, col = e & 63;
        out[base + (long)(c0 + row) * Rr + r0 + col] = f2bf(Ls[col][row]);
    }
}

__global__ __launch_bounds__(256) void transconv_kernel(
    const float* __restrict__ in, bf16_t* __restrict__ out, int Rr, int Cc)
{
    __shared__ float Ls[64][65];
    const int tid = threadIdx.x;
    const long base = (long)blockIdx.z * Rr * Cc;
    const int r0 = blockIdx.y * 64, c0 = blockIdx.x * 64;
    #pragma unroll
    for (int i = 0; i < 16; ++i) {
        int e = tid + i * 256; int row = e >> 6, col = e & 63;
        Ls[row][col] = in[base + (long)(r0 + row) * Cc + c0 + col];
    }
    __syncthreads();
    #pragma unroll
    for (int i = 0; i < 16; ++i) {
        int e = tid + i * 256; int row = e >> 6, col = e & 63;
        out[base + (long)(c0 + row) * Rr + r0 + col] = f2bf(Ls[col][row]);
    }
}

// ---------------- fused relation weights (+bias, folded) ----------------
__global__ __launch_bounds__(256) void fuse_wT_kernel(
    const float* __restrict__ Wk, const float* __restrict__ Wv,
    const float* __restrict__ bk, const float* __restrict__ bv,
    const float* __restrict__ a_rel, const float* __restrict__ m_rel,
    bf16_t* __restrict__ WkvT, float* __restrict__ bkv)
{
    const int s = blockIdx.z;
    const int kv = s & 1, r = (s >> 1) & 3, l = s >> 3;
    const int SRCT[4] = {0, 1, 1, 1};
    const int st = SRCT[r];
    const float* W = (kv ? Wv : Wk) + ((long)l * T_ + st) * H_ * H_;
    const float* A = (kv ? m_rel : a_rel) + ((long)l * R_ + r) * HEADS_ * D_ * D_;
    const int hh = blockIdx.y, kt = blockIdx.x;
    __shared__ float As[32][33];
    __shared__ float Ws[64][33];
    const int tid = threadIdx.x;
    {
        int d = tid >> 3, e4 = (tid & 7) * 4;
        float4 v = *(const float4*)(A + (hh * D_ + d) * D_ + e4);
        As[d][e4] = v.x; As[d][e4 + 1] = v.y; As[d][e4 + 2] = v.z; As[d][e4 + 3] = v.w;
    }
    #pragma unroll
    for (int p = 0; p < 2; ++p) {
        int idx = p * 256 + tid;
        int row = idx >> 3, c4 = (idx & 7) * 4;
        float4 v = *(const float4*)(W + (long)(kt * 64 + row) * H_ + hh * 32 + c4);
        Ws[row][c4] = v.x; Ws[row][c4 + 1] = v.y; Ws[row][c4 + 2] = v.z; Ws[row][c4 + 3] = v.w;
    }
    __syncthreads();
    const int kl = tid & 63, eb = tid >> 6;
    #pragma unroll
    for (int ii = 0; ii < 8; ++ii) {
        int e = eb * 8 + ii;
        float acc = 0.f;
        #pragma unroll
        for (int d = 0; d < 32; ++d)
            acc += As[d][e] * Ws[kl][d];
        long rowIdx = (long)(s >> 1) * 512 + (kv * 256) + hh * 32 + e;
        WkvT[rowIdx * H_ + kt * 64 + kl] = f2bf(acc);
    }
    // folded bias fusion (one block per s)
    if (blockIdx.x == 0 && blockIdx.y == 0) {
        const float* b = (kv ? bv : bk) + ((long)l * T_ + st) * H_;
        const int bh = tid >> 5, be = tid & 31;
        float acc = 0.f;
        #pragma unroll
        for (int d = 0; d < D_; ++d)
            acc += b[bh * D_ + d] * A[(bh * D_ + d) * D_ + be];
        bkv[(long)(s >> 1) * 512 + kv * 256 + tid] = acc;
    }
}

// ---------------- CSR build (parallel scan) ----------------
__global__ void hist_kernel(const int* __restrict__ ei, int* __restrict__ indeg,
                            int Nn, int E)
{
    int idx = blockIdx.x * 256 + threadIdx.x;
    if (idx >= R_ * E) return;
    int r = idx / E, e = idx - r * E;
    int d = ei[(size_t)r * 2 * E + E + e];
    atomicAdd(indeg + (size_t)r * Nn + d, 1);
}

__global__ __launch_bounds__(256) void csr_part_kernel(
    const int* __restrict__ indeg, int* __restrict__ partials, int Nn, int nch)
{
    const int r = blockIdx.y, c = blockIdx.x, tid = threadIdx.x;
    const int lane = tid & 63, wave = tid >> 6;
    int idx = c * 256 + tid;
    int v = (idx < Nn) ? indeg[(size_t)r * Nn + idx] : 0;
    #pragma unroll
    for (int off = 1; off < 64; off <<= 1) v += __shfl_xor(v, off);
    __shared__ int wsum[4];
    if (lane == 0) wsum[wave] = v;
    __syncthreads();
    if (tid == 0) partials[r * nch + c] = wsum[0] + wsum[1] + wsum[2] + wsum[3];
}

__global__ __launch_bounds__(256) void csr_scanpart_kernel(
    int* __restrict__ partials, int nch)
{
    const int r = blockIdx.x, tid = threadIdx.x;
    __shared__ int sh[256];
    int v = (tid < nch) ? partials[r * nch + tid] : 0;
    sh[tid] = v;
    __syncthreads();
    for (int off = 1; off < 256; off <<= 1) {
        int u = (tid >= off) ? sh[tid - off] : 0;
        __syncthreads();
        sh[tid] += u;
        __syncthreads();
    }
    if (tid < nch) partials[r * nch + tid] = sh[tid] - v;   // exclusive
}

__global__ __launch_bounds__(256) void csr_write_kernel(
    const int* __restrict__ indeg, const int* __restrict__ partials,
    int* __restrict__ offs, int* __restrict__ cursor, int Nn, int nch)
{
    const int r = blockIdx.y, c = blockIdx.x, tid = threadIdx.x;
    int idx = c * 256 + tid;
    int v = (idx < Nn) ? indeg[(size_t)r * Nn + idx] : 0;
    __shared__ int sh[256];
    sh[tid] = v;
    __syncthreads();
    for (int off = 1; off < 256; off <<= 1) {
        int u = (tid >= off) ? sh[tid - off] : 0;
        __syncthreads();
        sh[tid] += u;
        __syncthreads();
    }
    int incl = sh[tid];
    int base = partials[r * nch + c];
    if (idx < Nn) {
        int excl = base + incl - v;
        offs[(size_t)r * (Nn + 1) + idx] = excl;
        cursor[(size_t)r * Nn + idx] = excl;
        if (idx == Nn - 1) offs[(size_t)r * (Nn + 1) + Nn] = base + incl;
    }
}

__global__ void scatter_kernel(const int* __restrict__ ei, int* __restrict__ cursor,
                               int* __restrict__ esrc, int Nn, int E)
{
    int idx = blockIdx.x * 256 + threadIdx.x;
    if (idx >= R_ * E) return;
    int r = idx / E, e = idx - r * E;
    int s = ei[(size_t)r * 2 * E + e];
    int d = ei[(size_t)r * 2 * E + E + e];
    int pos = atomicAdd(cursor + (size_t)r * Nn + d, 1);
    esrc[(size_t)r * E + pos] = s;
}

// ---------------- batched per-node attention aggregation (dual-chain ILP) ----------------
// Per-relation INDEPENDENT softmax; normalized results summed (matches ref).
// Two concurrent online-softmax chains per wave:
//   2-relation group: chain A = rel0, chain B = rel1 (normalize separately, add)
//   1-relation group: range split in half, chains merged exactly before normalize
__global__ __launch_bounds__(256) void agg_all_kernel(
    const int* __restrict__ offs, const int* __restrict__ esrc,
    bf16_t* __restrict__ qbuf, const bf16_t* __restrict__ KV,
    const float* __restrict__ p_l, float scale, int Nn, int E)
{
    static const int NRELg[3] = {2, 1, 1};
    static const int R0g[3]  = {0, 1, 3};
    static const int R1g[3]  = {2, 0, 0};
    static const int DTg[3]  = {1, 0, 2};
    const int grp = blockIdx.y;
    const int wave = threadIdx.x >> 6, lane = threadIdx.x & 63;
    const int d = blockIdx.x * 4 + wave;
    if (d >= Nn) return;
    const int head = lane >> 3;
    const int dt = DTg[grp];

    bf16_t* qrow = qbuf + (size_t)dt * Nn * H_ + (size_t)d * H_;
    ushort4 qu = ((const ushort4*)qrow)[lane];
    float q0 = bf2f(qu.x), q1 = bf2f(qu.y), q2 = bf2f(qu.z), q3 = bf2f(qu.w);

    // chain A = first relation
    const int rA = R0g[grp];
    const int* esA = esrc + (size_t)rA * E;
    const bf16_t* kvA = KV + (size_t)rA * Nn * 512;
    float prA = p_l[rA * HEADS_ + head] * scale;
    int curA = offs[(size_t)rA * (Nn + 1) + d];
    int endA = offs[(size_t)rA * (Nn + 1) + d + 1];

    const int* esB; const bf16_t* kvB; float prB;
    int curB, endB;
    const bool separate = (NRELg[grp] == 2);
    if (separate) {
        const int rB = R1g[grp];
        esB = esrc + (size_t)rB * E;
        kvB = KV + (size_t)rB * Nn * 512;
        prB = p_l[rB * HEADS_ + head] * scale;
        curB = offs[(size_t)rB * (Nn + 1) + d];
        endB = offs[(size_t)rB * (Nn + 1) + d + 1];
    } else {
        int mid = curA + ((endA - curA + 1) >> 1);
        esB = esA; kvB = kvA; prB = prA;
        curB = mid; endB = endA;
        endA = mid;
    }

    float mA = -INFINITY, sA = 0.f, aA0 = 0.f, aA1 = 0.f, aA2 = 0.f, aA3 = 0.f;
    float mB = -INFINITY, sB = 0.f, aB0 = 0.f, aB1 = 0.f, aB2 = 0.f, aB3 = 0.f;

    while (curA < endA || curB < endB) {
        const bool hA = curA < endA, hB = curB < endB;
        ushort4 kuA, vuA, kuB, vuB;
        if (hA) {
            const bf16_t* row = kvA + (size_t)esA[curA] * 512;
            kuA = ((const ushort4*)row)[lane];
            vuA = ((const ushort4*)(row + 256))[lane];
        }
        if (hB) {
            const bf16_t* row = kvB + (size_t)esB[curB] * 512;
            kuB = ((const ushort4*)row)[lane];
            vuB = ((const ushort4*)(row + 256))[lane];
        }
        if (hA) {
            float dt_ = q0 * bf2f(kuA.x) + q1 * bf2f(kuA.y) + q2 * bf2f(kuA.z) + q3 * bf2f(kuA.w);
            dt_ += __shfl_xor(dt_, 1);
            dt_ += __shfl_xor(dt_, 2);
            dt_ += __shfl_xor(dt_, 4);
            float lg = dt_ * prA;
            float mnew = fmaxf(mA, lg);
            float fac = __expf(mA - mnew);
            float p = __expf(lg - mnew);
            sA = sA * fac + p;
            aA0 = aA0 * fac + p * bf2f(vuA.x);
            aA1 = aA1 * fac + p * bf2f(vuA.y);
            aA2 = aA2 * fac + p * bf2f(vuA.z);
            aA3 = aA3 * fac + p * bf2f(vuA.w);
            mA = mnew;
            ++curA;
        }
        if (hB) {
            float dt_ = q0 * bf2f(kuB.x) + q1 * bf2f(kuB.y) + q2 * bf2f(kuB.z) + q3 * bf2f(kuB.w);
            dt_ += __shfl_xor(dt_, 1);
            dt_ += __shfl_xor(dt_, 2);
            dt_ += __shfl_xor(dt_, 4);
            float lg = dt_ * prB;
            float mnew = fmaxf(mB, lg);
            float fac = __expf(mB - mnew);
            float p = __expf(lg - mnew);
            sB = sB * fac + p;
            aB0 = aB0 * fac + p * bf2f(vuB.x);
            aB1 = aB1 * fac + p * bf2f(vuB.y);
            aB2 = aB2 * fac + p * bf2f(vuB.z);
            aB3 = aB3 * fac + p * bf2f(vuB.w);
            mB = mnew;
            ++curB;
        }
    }

    float t0, t1, t2, t3;
    if (separate) {
        float iA = (sA > 0.f) ? 1.f / sA : 0.f;
        float iB = (sB > 0.f) ? 1.f / sB : 0.f;
        t0 = aA0 * iA + aB0 * iB;
        t1 = aA1 * iA + aB1 * iB;
        t2 = aA2 * iA + aB2 * iB;
        t3 = aA3 * iA + aB3 * iB;
    } else {
        if (sB > 0.f) {   // exact merge of the two half-range chains
            float m = fmaxf(mA, mB);
            float fA = (sA > 0.f) ? __expf(mA - m) : 0.f;
            float fB = __expf(mB - m);
            sA = sA * fA + sB * fB;
            aA0 = aA0 * fA + aB0 * fB;
            aA1 = aA1 * fA + aB1 * fB;
            aA2 = aA2 * fA + aB2 * fB;
            aA3 = aA3 * fA + aB3 * fB;
        }
        float iA = (sA > 0.f) ? 1.f / sA : 0.f;
        t0 = aA0 * iA; t1 = aA1 * iA; t2 = aA2 * iA; t3 = aA3 * iA;
    }
    ushort4 ou;
    ou.x = f2bf(gelu_exact(t0));
    ou.y = f2bf(gelu_exact(t1));
    ou.z = f2bf(gelu_exact(t2));
    ou.w = f2bf(gelu_exact(t3));
    ((ushort4*)qrow)[lane] = ou;
}

// ---------------- MFMA bf16 GEMM ----------------
// C[M,Nc] = actC( A[M,K] @ BT[Nc,K]^T + bias[Nc] ), batched over z.
// A-select: z < zsplit -> A + z*strideA ; else -> A2 (stride 0).
#define ASTR 40
#define ESTR 72

template<typename TA, typename TC, int ACT_C>
__global__ __launch_bounds__(256) void mfma_gemm(
    const TA* __restrict__ A, const TA* __restrict__ A2, int zsplit,
    const bf16_t* __restrict__ BT,
    const float* __restrict__ bias, TC* __restrict__ C,
    int M, int K, int Nc,
    long strideA, long strideB, long strideBias, long strideC)
{
    // bijective XCD-chunked swizzle: same-y blocks contiguous per XCD
    const int gX = gridDim.x, gY = gridDim.y, gZ = gridDim.z;
    const int nwg = gX * gY * gZ;
    int flat = blockIdx.x + gX * (blockIdx.y + gY * blockIdx.z);
    const int qch = nwg >> 3, rch = nwg & 7;
    int xcd = flat & 7, cidx = flat >> 3;
    int swz = (xcd < rch ? xcd * (qch + 1) : rch * (qch + 1) + (xcd - rch) * qch) + cidx;
    const int by = swz / (gX * gZ);
    int rem = swz - by * (gX * gZ);
    const int bz = rem / gX;
    const int bx = rem - bz * gX;

    const TA* Ab = (bz < zsplit) ? (A + (long)bz * strideA) : A2;
    const bf16_t* Bb = BT + (long)bz * strideB;
    const float* biasb = bias + (long)bz * strideBias;
    TC* Cb = C + (long)bz * strideC;

    __shared__ bf16_t As[128 * ASTR];
    __shared__ bf16_t Bs[128 * ASTR];
    __shared__ bf16_t Es[4 * 16 * ESTR];
    const int tid = threadIdx.x;
    const int lane = tid & 63, wave = tid >> 6;
    const int wr = wave >> 1, wc = wave & 1;
    const int bm = by * 128, bn = bx * 128;
    const int r16 = lane & 15, g = lane >> 4;
    f32x4 acc[4][4] = {};

    for (int k0 = 0; k0 < K; k0 += 32) {
        #pragma unroll
        for (int p = 0; p < 2; ++p) {
            int idx = p * 256 + tid;
            int row = idx >> 2, seg = idx & 3;
            int grow = bm + row;
            bf16x8 av = {};
            if (grow < M) {
                if constexpr (sizeof(TA) == 2) {
                    av = *(const bf16x8*)(Ab + (long)grow * K + k0 + seg * 8);
                } else {
                    const float* sp = (const float*)Ab + (long)grow * K + k0 + seg * 8;
                    float4 f0 = *(const float4*)sp, f1 = *(const float4*)(sp + 4);
                    av[0] = (short)f2bf(f0.x); av[1] = (short)f2bf(f0.y);
                    av[2] = (short)f2bf(f0.z); av[3] = (short)f2bf(f0.w);
                    av[4] = (short)f2bf(f1.x); av[5] = (short)f2bf(f1.y);
                    av[6] = (short)f2bf(f1.z); av[7] = (short)f2bf(f1.w);
                }
            }
            *(bf16x8*)(As + row * ASTR + seg * 8) = av;
            bf16x8 bv = *(const bf16x8*)(Bb + (long)(bn + row) * K + k0 + seg * 8);
            *(bf16x8*)(Bs + row * ASTR + seg * 8) = bv;
        }
        __syncthreads();
        bf16x8 af[4], bfr[4];
        #pragma unroll
        for (int m = 0; m < 4; ++m)
            af[m] = *(const bf16x8*)(As + (wr * 64 + m * 16 + r16) * ASTR + g * 8);
        #pragma unroll
        for (int n = 0; n < 4; ++n)
            bfr[n] = *(const bf16x8*)(Bs + (wc * 64 + n * 16 + r16) * ASTR + g * 8);
        #pragma unroll
        for (int m = 0; m < 4; ++m)
            #pragma unroll
            for (int n = 0; n < 4; ++n)
                acc[m][n] = __builtin_amdgcn_mfma_f32_16x16x32_bf16(af[m], bfr[n], acc[m][n], 0, 0, 0);
        __syncthreads();
    }

    float bb[4];
    #pragma unroll
    for (int n = 0; n < 4; ++n)
        bb[n] = biasb[bn + wc * 64 + n * 16 + r16];

    if constexpr (sizeof(TC) == 2) {
        bf16_t* st = Es + wave * (16 * ESTR);
        #pragma unroll
        for (int m = 0; m < 4; ++m) {
            int rowbase = bm + wr * 64 + m * 16;
            #pragma unroll
            for (int n = 0; n < 4; ++n) {
                #pragma unroll
                for (int j = 0; j < 4; ++j) {
                    float vv = acc[m][n][j] + bb[n];
                    if (ACT_C) vv = fmaxf(vv, 0.f);
                    st[(g * 4 + j) * ESTR + n * 16 + r16] = f2bf(vv);
                }
            }
            #pragma unroll
            for (int p = 0; p < 2; ++p) {
                int row = p * 8 + (lane >> 3);
                int col0 = (lane & 7) * 8;
                int grow = rowbase + row;
                bf16x8 val = *(const bf16x8*)(st + row * ESTR + col0);
                if (grow < M)
                    *(bf16x8*)(Cb + (long)grow * Nc + bn + wc * 64 + col0) = val;
            }
        }
    } else {
        #pragma unroll
        for (int n = 0; n < 4; ++n) {
            int col = bn + wc * 64 + n * 16 + r16;
            #pragma unroll
            for (int m = 0; m < 4; ++m) {
                int rowbase = bm + wr * 64 + m * 16 + g * 4;
                #pragma unroll
                for (int j = 0; j < 4; ++j) {
                    int row = rowbase + j;
                    if (row < M) {
                        float vv = acc[m][n][j] + bb[n];
                        if (ACT_C) vv = fmaxf(vv, 0.f);
                        Cb[(long)row * Nc + col] = vv;
                    }
                }
            }
        }
    }
}

// ---------------- fused skip-gate + residual + LN + ReLU ----------------
__global__ __launch_bounds__(256) void skip_ln_kernel(
    bf16_t* __restrict__ h, const bf16_t* __restrict__ o,
    const float* __restrict__ skip, const float* __restrict__ ln_g,
    const float* __restrict__ ln_b, int Nn)
{
    const int wave = threadIdx.x >> 6;
    const int lane = threadIdx.x & 63;
    long row = (long)blockIdx.x * 4 + wave;
    long total = (long)T_ * Nn;
    if (row >= total) return;
    int t = (int)(row / Nn);
    float beta = 1.f / (1.f + expf(-skip[t]));
    float cb = 2.f - beta;
    ushort4 hv = reinterpret_cast<const ushort4*>(h + row * H_)[lane];
    ushort4 ov = reinterpret_cast<const ushort4*>(o + row * H_)[lane];
    float u0 = beta * bf2f(ov.x) + cb * bf2f(hv.x);
    float u1 = beta * bf2f(ov.y) + cb * bf2f(hv.y);
    float u2 = beta * bf2f(ov.z) + cb * bf2f(hv.z);
    float u3 = beta * bf2f(ov.w) + cb * bf2f(hv.w);
    float s1 = u0 + u1 + u2 + u3;
    float s2 = u0 * u0 + u1 * u1 + u2 * u2 + u3 * u3;
    #pragma unroll
    for (int off = 1; off < 64; off <<= 1) {
        s1 += __shfl_xor(s1, off);
        s2 += __shfl_xor(s2, off);
    }
    float mu = s1 * (1.f / H_);
    float var = s2 * (1.f / H_) - mu * mu;
    float inv = rsqrtf(var + 1e-5f);
    const float4 g = reinterpret_cast<const float4*>(ln_g + (size_t)t * H_)[lane];
    const float4 b = reinterpret_cast<const float4*>(ln_b + (size_t)t * H_)[lane];
    ushort4 r;
    r.x = f2bf(fmaxf((u0 - mu) * inv * g.x + b.x, 0.f));
    r.y = f2bf(fmaxf((u1 - mu) * inv * g.y + b.y, 0.f));
    r.z = f2bf(fmaxf((u2 - mu) * inv * g.z + b.z, 0.f));
    r.w = f2bf(fmaxf((u3 - mu) * inv * g.w + b.w, 0.f));
    reinterpret_cast<ushort4*>(h + row * H_)[lane] = r;
}

// ---------------- host side ----------------
extern "C" void kernel_launch(void* const* d_in, const int* in_sizes, int n_in,
                              void* d_out, int out_size, void* d_ws, size_t ws_size,
                              hipStream_t stream)
{
    const float* x     = (const float*)d_in[0];
    const int*   ei    = (const int*)  d_in[1];
    const float* Win   = (const float*)d_in[2];
    const float* b_in  = (const float*)d_in[3];
    const float* Wk    = (const float*)d_in[4];
    const float* bk    = (const float*)d_in[5];
    const float* Wq    = (const float*)d_in[6];
    const float* bq    = (const float*)d_in[7];
    const float* Wv    = (const float*)d_in[8];
    const float* bv    = (const float*)d_in[9];
    const float* Wa    = (const float*)d_in[10];
    const float* ba    = (const float*)d_in[11];
    const float* skip  = (const float*)d_in[12];
    const float* a_rel = (const float*)d_in[13];
    const float* m_rel = (const float*)d_in[14];
    const float* p_rel = (const float*)d_in[15];
    const float* ln_g  = (const float*)d_in[16];
    const float* ln_b  = (const float*)d_in[17];
    const float* Wout  = (const float*)d_in[18];
    const float* bout  = (const float*)d_in[19];
    float* out = (float*)d_out;

    const int N = in_sizes[0] / (T_ * FIN_);
    const int E = in_sizes[1] / (R_ * 2);
    const size_t NH = (size_t)N * H_;
    const int nch = (N + 255) / 256;
    const int ZBIG = 1 << 20;

    char* wp = (char*)d_ws;
    auto alloc = [&](size_t bytes) {
        void* r = wp;
        wp += (bytes + 255) & ~(size_t)255;
        return r;
    };
    bf16_t* h     = (bf16_t*)alloc(T_ * NH * 2);
    bf16_t* qbuf  = (bf16_t*)alloc(T_ * NH * 2);
    bf16_t* KV    = (bf16_t*)alloc((size_t)R_ * N * 512 * 2);
    int*    indeg = (int*)   alloc((size_t)R_ * N * 4);
    int*    offs  = (int*)   alloc((size_t)R_ * (N + 1) * 4);
    int*    cursor= (int*)   alloc((size_t)R_ * N * 4);
    int*    esrc  = (int*)   alloc((size_t)R_ * E * 4);
    int*    parts = (int*)   alloc((size_t)R_ * 256 * 4);
    bf16_t* WqT   = (bf16_t*)alloc((size_t)L_ * T_ * H_ * H_ * 2);
    bf16_t* WaT   = (bf16_t*)alloc((size_t)L_ * T_ * H_ * H_ * 2);
    bf16_t* WinT  = (bf16_t*)alloc((size_t)T_ * FIN_ * H_ * 2);
    bf16_t* WoutT = (bf16_t*)alloc((size_t)H_ * OUT_ * 2);
    bf16_t* WkvT  = (bf16_t*)alloc((size_t)L_ * R_ * 512 * H_ * 2);
    float*  bkv   = (float*) alloc((size_t)L_ * R_ * 512 * 4);

    bf16_t* obuf = KV;   // reuse of KV after agg consumes it

    if ((size_t)(wp - (char*)d_ws) > ws_size) return;   // clean-fail guard

    const float scale = 0.17677669529663688f;  // 1/sqrt(32)
    dim3 blk(256);
    auto gM = [](long M) { return (int)((M + 127) / 128); };

    // ---- weight preprocessing ----
    transconv2_kernel<<<dim3(4, 4, 2 * L_ * T_), blk, 0, stream>>>(
        Wq, WqT, Wa, WaT, L_ * T_, H_, H_);
    transconv_kernel<<<dim3(4, 2, T_), blk, 0, stream>>>(Win, WinT, FIN_, H_);
    transconv_kernel<<<dim3(2, 4, 1),  blk, 0, stream>>>(Wout, WoutT, H_, OUT_);
    fuse_wT_kernel<<<dim3(4, 8, 16), blk, 0, stream>>>(
        Wk, Wv, bk, bv, a_rel, m_rel, WkvT, bkv);

    // ---- CSR build (parallel) ----
    zero_kernel<<<256, blk, 0, stream>>>((unsigned*)indeg, (long)R_ * N);
    hist_kernel<<<(R_ * E + 255) / 256, blk, 0, stream>>>(ei, indeg, N, E);
    csr_part_kernel<<<dim3(nch, R_), blk, 0, stream>>>(indeg, parts, N, nch);
    csr_scanpart_kernel<<<R_, blk, 0, stream>>>(parts, nch);
    csr_write_kernel<<<dim3(nch, R_), blk, 0, stream>>>(indeg, parts, offs, cursor, N, nch);
    scatter_kernel<<<(R_ * E + 255) / 256, blk, 0, stream>>>(ei, cursor, esrc, N, E);

    // ---- input projection + relu ----
    mfma_gemm<float, bf16_t, 1><<<dim3(H_ / 128, gM(N), T_), blk, 0, stream>>>(
        x, x, ZBIG, WinT, b_in, h, N, FIN_, H_,
        (long)N * FIN_, (long)FIN_ * H_, H_, (long)NH);

    for (int l = 0; l < L_; ++l) {
        const long lw = (long)l * R_;
        // KV for all 4 relations in one z=4 launch: z=0 -> h(type0), z>=1 -> h(type1)
        mfma_gemm<bf16_t, bf16_t, 0><<<dim3(512 / 128, gM(N), 4), blk, 0, stream>>>(
            h, h + NH, 1, WkvT + lw * 512 * H_, bkv + lw * 512, KV,
            N, H_, 512, 0L, 512L * H_, 512L, (long)N * 512);
        // q for all 3 node types: z=3
        mfma_gemm<bf16_t, bf16_t, 0><<<dim3(H_ / 128, gM(N), 3), blk, 0, stream>>>(
            h, h, ZBIG, WqT + (size_t)l * T_ * H_ * H_, bq + (size_t)l * T_ * H_, qbuf,
            N, H_, H_, (long)NH, (long)H_ * H_, (long)H_, (long)NH);
        // batched per-node per-relation softmax aggregation + GELU (in place)
        agg_all_kernel<<<dim3((N + 3) / 4, 3), blk, 0, stream>>>(
            offs, esrc, qbuf, KV, p_rel + (size_t)l * R_ * HEADS_, scale, N, E);
        // o[t] = aggb[t] @ Wa[t] + ba[t] : z=3
        mfma_gemm<bf16_t, bf16_t, 0><<<dim3(H_ / 128, gM(N), 3), blk, 0, stream>>>(
            qbuf, qbuf, ZBIG, WaT + (size_t)l * T_ * H_ * H_, ba + (size_t)l * T_ * H_, obuf,
            N, H_, H_, (long)NH, (long)H_ * H_, (long)H_, (long)NH);
        // skip-gate + residual + LN + ReLU
        skip_ln_kernel<<<((size_t)T_ * N + 3) / 4, blk, 0, stream>>>(
            h, obuf, skip + l * T_, ln_g + (size_t)l * T_ * H_, ln_b + (size_t)l * T_ * H_, N);
    }

    // shared output projection: h bf16 -> out fp32
    mfma_gemm<bf16_t, float, 0><<<dim3(OUT_ / 128, gM((long)T_ * N), 1), blk, 0, stream>>>(
        h, h, ZBIG, WoutT, bout, out, T_ * N, H_, OUT_, 0L, 0L, 0L, 0L);
}